// Round 1
// baseline (672.532 us; speedup 1.0000x reference)
//
#include <hip/hip_runtime.h>

typedef __attribute__((ext_vector_type(8))) short bf16x8;
typedef __attribute__((ext_vector_type(4))) float f32x4;

#define S_LEN  2048
#define HID    4096
#define NHEADS 32
#define NKVH   8
#define HDIM   128
#define QKVN   (HID + 2*NKVH*HDIM)   // 6144
#define KOFS   HID                   // K cols start at 4096 in QKV buffer
#define VOFS   (HID + NKVH*HDIM)     // V cols start at 5120

__device__ __forceinline__ unsigned short f2bf(float f){
  unsigned int x = __float_as_uint(f);
  x += 0x7fffu + ((x >> 16) & 1u);
  return (unsigned short)(x >> 16);
}
__device__ __forceinline__ float bf2f(unsigned short h){
  return __uint_as_float(((unsigned int)h) << 16);
}

// ---------------- fp32 -> bf16 conversion ----------------
__global__ void cvt_f32_bf16(const float* __restrict__ src, unsigned short* __restrict__ dst, int n4){
  int i = blockIdx.x * blockDim.x + threadIdx.x;
  if (i < n4){
    float4 v = *(const float4*)(src + (size_t)i*4);
    ushort4 o;
    o.x = f2bf(v.x); o.y = f2bf(v.y); o.z = f2bf(v.z); o.w = f2bf(v.w);
    *(ushort4*)(dst + (size_t)i*4) = o;
  }
}

// ---------------- RoPE ----------------
__global__ void rope_table(float* __restrict__ cosT, float* __restrict__ sinT){
  int idx = blockIdx.x * blockDim.x + threadIdx.x;   // S_LEN*64
  int s = idx >> 6, i = idx & 63;
  // inv_freq = theta^(-2i/128) ; ln(500000) = 13.122363377404329
  float inv = expf(-(float)i * (13.122363377404329f / 64.0f));
  float a = (float)s * inv;
  cosT[idx] = cosf(a);
  sinT[idx] = sinf(a);
}

__global__ void rope_apply(unsigned short* __restrict__ X, const float* __restrict__ cosT,
                           const float* __restrict__ sinT, int nh, int rowstr, int colofs, int total){
  int idx = blockIdx.x * blockDim.x + threadIdx.x;
  if (idx >= total) return;
  int i = idx & 63;
  int h = (idx >> 6) % nh;
  int s = idx / (64*nh);
  size_t base = (size_t)s*rowstr + colofs + h*HDIM + i;
  float x0 = bf2f(X[base]), x1 = bf2f(X[base+64]);
  float c = cosT[(s<<6)|i], sn = sinT[(s<<6)|i];
  X[base]    = f2bf(x0*c - x1*sn);
  X[base+64] = f2bf(x1*c + x0*sn);
}

// ---------------- bf16 GEMM: C[M,N] = A[M,K] @ W[N,K]^T ----------------
// m97 structure: 128x128 tile, BK=32, global_load_lds width 16, 4 waves 2x2.
template<int OUTF32>
__global__ __launch_bounds__(256) void gemm_bt(const unsigned short* __restrict__ A,
                                               const unsigned short* __restrict__ W,
                                               void* __restrict__ C, int M, int N, int K){
  __shared__ unsigned short As[128*32];
  __shared__ unsigned short Ws[128*32];
  const int tid = threadIdx.x;
  const int lane = tid & 63, wv = tid >> 6;
  const int tn = blockIdx.x, tm = blockIdx.y;
  const int wr = wv >> 1, wc = wv & 1;
  const int r = lane & 15, kq = lane >> 4;
  f32x4 acc[4][4];
  #pragma unroll
  for (int m=0;m<4;m++)
    #pragma unroll
    for (int n=0;n<4;n++) acc[m][n] = {0.f,0.f,0.f,0.f};
  const unsigned short* Ab = A + (size_t)tm*128*K;
  const unsigned short* Wb = W + (size_t)tn*128*K;
  for (int kt = 0; kt < K; kt += 32){
    #pragma unroll
    for (int i=0;i<2;i++){
      int ch = i*4 + wv;                 // 8 chunks of 1024B per 8KB tile
      int o = (ch<<10) + lane*16;        // byte offset in tile (per-lane, for global src)
      int row = o >> 6;                  // 64B per row (32 bf16)
      int cole = (o & 63) >> 1;          // element col within row
      __builtin_amdgcn_global_load_lds(
        (const __attribute__((address_space(1))) void*)(Ab + (size_t)row*K + kt + cole),
        (__attribute__((address_space(3))) void*)((char*)As + (ch<<10)), 16, 0, 0);
      __builtin_amdgcn_global_load_lds(
        (const __attribute__((address_space(1))) void*)(Wb + (size_t)row*K + kt + cole),
        (__attribute__((address_space(3))) void*)((char*)Ws + (ch<<10)), 16, 0, 0);
    }
    __syncthreads();
    bf16x8 av[4], bv[4];
    #pragma unroll
    for (int m=0;m<4;m++) av[m] = *(const bf16x8*)&As[(wr*64 + m*16 + r)*32 + kq*8];
    #pragma unroll
    for (int n=0;n<4;n++) bv[n] = *(const bf16x8*)&Ws[(wc*64 + n*16 + r)*32 + kq*8];
    #pragma unroll
    for (int m=0;m<4;m++)
      #pragma unroll
      for (int n=0;n<4;n++)
        acc[m][n] = __builtin_amdgcn_mfma_f32_16x16x32_bf16(av[m], bv[n], acc[m][n], 0, 0, 0);
    __syncthreads();
  }
  #pragma unroll
  for (int m=0;m<4;m++)
    #pragma unroll
    for (int n=0;n<4;n++)
      #pragma unroll
      for (int j=0;j<4;j++){
        int gr = tm*128 + wr*64 + m*16 + kq*4 + j;
        int gc = tn*128 + wc*64 + n*16 + r;
        if (OUTF32) ((float*)C)[(size_t)gr*N + gc] = acc[m][n][j];
        else ((unsigned short*)C)[(size_t)gr*N + gc] = f2bf(acc[m][n][j]);
      }
}

// ---------------- causal GQA flash attention ----------------
// grid (S/64, NHEADS), 256 threads. Wave w owns q rows [qt*64+w*16, +16).
// QKV: [S][6144] bf16 (Q cols 0..4095, K cols 4096..5119, V cols 5120..6143)
__global__ __launch_bounds__(256) void attn_fwd(const unsigned short* __restrict__ QKV,
                                                unsigned short* __restrict__ AO){
  __shared__ unsigned short Vt[128][40];      // transposed V tile [d][kv^swz], stride 40 (16B-aligned rows)
  __shared__ unsigned short Pl[4][16][40];    // per-wave P tile [q][kv]
  const int tid = threadIdx.x;
  const int lane = tid & 63, wv = tid >> 6;
  const int qt = blockIdx.x, h = blockIdx.y;
  const int kvh = h >> 2;                     // GQA: 4 q-heads per kv-head
  const int q0 = qt*64 + wv*16;
  const int r = lane & 15, kq = lane >> 4;
  const float scale = 0.08838834764831845f;   // 1/sqrt(128)
  const float L2E = 1.44269504088896f;

  bf16x8 qf[4];
  #pragma unroll
  for (int kc=0;kc<4;kc++)
    qf[kc] = *(const bf16x8*)&QKV[(size_t)(q0 + r)*QKVN + h*HDIM + kc*32 + kq*8];

  f32x4 oacc[8];
  #pragma unroll
  for (int d=0;d<8;d++) oacc[d] = {0.f,0.f,0.f,0.f};
  float mrow[4] = {-3e38f,-3e38f,-3e38f,-3e38f};
  float lsum[4] = {0.f,0.f,0.f,0.f};

  const int ntiles = 2*qt + 2;                // kv tiles of 32 up to qt*64+63
  for (int t=0;t<ntiles;t++){
    const int kv0 = t*32;
    __syncthreads();                          // previous tile's Vt reads done
    // stage V transposed with kv-index XOR swizzle (conflict-free writes & reads)
    #pragma unroll
    for (int it=0;it<2;it++){
      int kv = it*16 + (tid >> 4);
      int d0 = (tid & 15)*8;
      bf16x8 vvv = *(const bf16x8*)&QKV[(size_t)(kv0+kv)*QKVN + VOFS + kvh*HDIM + d0];
      #pragma unroll
      for (int j=0;j<8;j++){
        int d = d0 + j;
        Vt[d][kv ^ (((d>>3)&3)<<3)] = (unsigned short)vvv[j];
      }
    }
    __syncthreads();
    // QK^T : two 16-kv-col fragments, K read direct from global (L2-resident)
    f32x4 s0 = {0.f,0.f,0.f,0.f}, s1 = {0.f,0.f,0.f,0.f};
    #pragma unroll
    for (int kc=0;kc<4;kc++){
      bf16x8 k0 = *(const bf16x8*)&QKV[(size_t)(kv0 + r)*QKVN      + KOFS + kvh*HDIM + kc*32 + kq*8];
      bf16x8 k1 = *(const bf16x8*)&QKV[(size_t)(kv0 + 16 + r)*QKVN + KOFS + kvh*HDIM + kc*32 + kq*8];
      s0 = __builtin_amdgcn_mfma_f32_16x16x32_bf16(qf[kc], k0, s0, 0, 0, 0);
      s1 = __builtin_amdgcn_mfma_f32_16x16x32_bf16(qf[kc], k1, s1, 0, 0, 0);
    }
    // online softmax (rows live in reg j, 16 lanes per row)
    float alpha[4];
    #pragma unroll
    for (int j=0;j<4;j++){
      int qg = q0 + kq*4 + j;
      float a = (kv0 + r      <= qg) ? s0[j]*scale : -3e38f;
      float b = (kv0 + 16 + r <= qg) ? s1[j]*scale : -3e38f;
      float mx = fmaxf(a, b);
      #pragma unroll
      for (int d=1; d<16; d<<=1) mx = fmaxf(mx, __shfl_xor(mx, d));
      float mnew = fmaxf(mrow[j], mx);
      alpha[j] = exp2f((mrow[j]-mnew)*L2E);
      float p0 = exp2f((a - mnew)*L2E);
      float p1 = exp2f((b - mnew)*L2E);
      float rs = p0 + p1;
      #pragma unroll
      for (int d=1; d<16; d<<=1) rs += __shfl_xor(rs, d);
      lsum[j] = lsum[j]*alpha[j] + rs;
      mrow[j] = mnew;
      Pl[wv][kq*4 + j][r]      = f2bf(p0);
      Pl[wv][kq*4 + j][16 + r] = f2bf(p1);
    }
    #pragma unroll
    for (int df=0;df<8;df++)
      #pragma unroll
      for (int j=0;j<4;j++) oacc[df][j] *= alpha[j];
    // PV: P via per-wave LDS re-layout (intra-wave DS ops are in-order)
    bf16x8 pa = *(const bf16x8*)&Pl[wv][r][kq*8];
    #pragma unroll
    for (int df=0;df<8;df++){
      int d = df*16 + r;
      int kvb = (kq*8) ^ (((d>>3)&3)<<3);
      bf16x8 vb = *(const bf16x8*)&Vt[d][kvb];
      oacc[df] = __builtin_amdgcn_mfma_f32_16x16x32_bf16(pa, vb, oacc[df], 0, 0, 0);
    }
  }
  // epilogue: normalize, write AO[s][h*128+d]
  #pragma unroll
  for (int df=0;df<8;df++)
    #pragma unroll
    for (int j=0;j<4;j++){
      int qg = q0 + kq*4 + j;
      AO[(size_t)qg*HID + h*HDIM + df*16 + r] = f2bf(oacc[df][j] / lsum[j]);
    }
}

// ---------------- launch ----------------
extern "C" void kernel_launch(void* const* d_in, const int* in_sizes, int n_in,
                              void* d_out, int out_size, void* d_ws, size_t ws_size,
                              hipStream_t stream){
  (void)in_sizes; (void)n_in; (void)out_size; (void)ws_size;
  const float* hs = (const float*)d_in[0];
  const float* Wq = (const float*)d_in[1];
  const float* Wk = (const float*)d_in[2];
  const float* Wv = (const float*)d_in[3];
  const float* Wo = (const float*)d_in[4];
  float* out = (float*)d_out;
  char* ws = (char*)d_ws;
  size_t off = 0;
  auto alloc = [&](size_t bytes)->void*{ void* p = ws + off; off += (bytes + 255) & ~(size_t)255; return p; };

  unsigned short* Hb    = (unsigned short*)alloc((size_t)S_LEN*HID*2);      // bf16 hidden
  unsigned short* Wqkvb = (unsigned short*)alloc((size_t)QKVN*HID*2);       // fused [6144][4096]
  unsigned short* Wob   = (unsigned short*)alloc((size_t)HID*HID*2);
  unsigned short* QKVb  = (unsigned short*)alloc((size_t)S_LEN*QKVN*2);     // [2048][6144]
  unsigned short* AOb   = (unsigned short*)alloc((size_t)S_LEN*HID*2);
  float* cosT = (float*)alloc((size_t)S_LEN*64*4);
  float* sinT = (float*)alloc((size_t)S_LEN*64*4);

  auto cvt = [&](const float* s, unsigned short* d, size_t n){
    int n4 = (int)(n/4);
    cvt_f32_bf16<<<(n4+255)/256, 256, 0, stream>>>(s, d, n4);
  };
  cvt(hs, Hb,  (size_t)S_LEN*HID);
  cvt(Wq, Wqkvb,                       (size_t)HID*HID);
  cvt(Wk, Wqkvb + (size_t)KOFS*HID,    (size_t)NKVH*HDIM*HID);
  cvt(Wv, Wqkvb + (size_t)VOFS*HID,    (size_t)NKVH*HDIM*HID);
  cvt(Wo, Wob, (size_t)HID*HID);
  rope_table<<<(S_LEN*64)/256, 256, 0, stream>>>(cosT, sinT);

  // fused QKV projection: [2048,6144] = Hb @ Wqkv^T
  gemm_bt<0><<<dim3(QKVN/128, S_LEN/128), 256, 0, stream>>>(Hb, Wqkvb, QKVb, S_LEN, QKVN, HID);

  int totQ = S_LEN*NHEADS*64;
  rope_apply<<<(totQ+255)/256, 256, 0, stream>>>(QKVb, cosT, sinT, NHEADS, QKVN, 0,    totQ);
  int totK = S_LEN*NKVH*64;
  rope_apply<<<(totK+255)/256, 256, 0, stream>>>(QKVb, cosT, sinT, NKVH,   QKVN, KOFS, totK);

  attn_fwd<<<dim3(S_LEN/64, NHEADS), 256, 0, stream>>>(QKVb, AOb);

  // output projection, fp32 epilogue straight into d_out
  gemm_bt<1><<<dim3(HID/128, S_LEN/128), 256, 0, stream>>>(AOb, Wob, out, S_LEN, HID, HID);
}

// Round 2
// 419.275 us; speedup vs baseline: 1.6040x; 1.6040x over previous
//
#include <hip/hip_runtime.h>

typedef __attribute__((ext_vector_type(8))) short bf16x8;
typedef __attribute__((ext_vector_type(4))) short bf16x4;
typedef __attribute__((ext_vector_type(4))) float f32x4;

#define S_LEN  2048
#define HID    4096
#define NHEADS 32
#define NKVH   8
#define HDIM   128
#define QKVN   (HID + 2*NKVH*HDIM)   // 6144
#define KOFS   HID                   // K cols start at 4096 in QKV buffer
#define VOFS   (HID + NKVH*HDIM)     // V cols start at 5120

#define AS1 __attribute__((address_space(1)))
#define AS3 __attribute__((address_space(3)))

__device__ __forceinline__ unsigned short f2bf(float f){
  unsigned int x = __float_as_uint(f);
  x += 0x7fffu + ((x >> 16) & 1u);
  return (unsigned short)(x >> 16);
}
__device__ __forceinline__ float bf2f(unsigned short h){
  return __uint_as_float(((unsigned int)h) << 16);
}

// ---------------- fp32 -> bf16 conversion ----------------
__global__ void cvt_f32_bf16(const float* __restrict__ src, unsigned short* __restrict__ dst, int n4){
  int i = blockIdx.x * blockDim.x + threadIdx.x;
  if (i < n4){
    float4 v = *(const float4*)(src + (size_t)i*4);
    ushort4 o;
    o.x = f2bf(v.x); o.y = f2bf(v.y); o.z = f2bf(v.z); o.w = f2bf(v.w);
    *(ushort4*)(dst + (size_t)i*4) = o;
  }
}

// ---------------- RoPE ----------------
__global__ void rope_table(float* __restrict__ cosT, float* __restrict__ sinT){
  int idx = blockIdx.x * blockDim.x + threadIdx.x;   // S_LEN*64
  int s = idx >> 6, i = idx & 63;
  float inv = expf(-(float)i * (13.122363377404329f / 64.0f));
  float a = (float)s * inv;
  cosT[idx] = cosf(a);
  sinT[idx] = sinf(a);
}

__global__ void rope_apply(unsigned short* __restrict__ X, const float* __restrict__ cosT,
                           const float* __restrict__ sinT, int nh, int rowstr, int colofs, int total){
  int idx = blockIdx.x * blockDim.x + threadIdx.x;
  if (idx >= total) return;
  int i = idx & 63;
  int h = (idx >> 6) % nh;
  int s = idx / (64*nh);
  size_t base = (size_t)s*rowstr + colofs + h*HDIM + i;
  float x0 = bf2f(X[base]), x1 = bf2f(X[base+64]);
  float c = cosT[(s<<6)|i], sn = sinT[(s<<6)|i];
  X[base]    = f2bf(x0*c - x1*sn);
  X[base+64] = f2bf(x1*c + x0*sn);
}

// ---------------- V transpose: Vt[kvh][d][s], s pi-permuted within 64-blocks ----
// pi(kv) = (kv&15)*4 + (kv>>4)  (within each 64-aligned block)
__global__ __launch_bounds__(256) void transpose_v(const unsigned short* __restrict__ QKV,
                                                   unsigned short* __restrict__ Vt){
  __shared__ unsigned short T[64][130];
  const int qt = blockIdx.x, kvh = blockIdx.y;
  const int tid = threadIdx.x;
  #pragma unroll
  for (int i=0;i<4;i++){
    int c = tid + i*256;          // 0..1023
    int sl = c >> 4;              // 0..63
    int d0 = (c & 15) * 8;
    bf16x8 v = *(const bf16x8*)&QKV[(size_t)(qt*64+sl)*QKVN + VOFS + kvh*HDIM + d0];
    #pragma unroll
    for (int j=0;j<8;j++) T[sl][d0+j] = (unsigned short)v[j];
  }
  __syncthreads();
  #pragma unroll
  for (int i=0;i<4;i++){
    int c = tid + i*256;
    int d = c >> 3;               // 0..127
    int p0 = (c & 7) * 8;         // pi-space position
    bf16x8 o;
    #pragma unroll
    for (int j=0;j<8;j++){
      int p = p0 + j;
      int s_nat = (p >> 2) + (p & 3) * 16;   // pi^-1(p)
      o[j] = (short)T[s_nat][d];
    }
    *(bf16x8*)&Vt[((size_t)kvh*HDIM + d)*S_LEN + qt*64 + p0] = o;
  }
}

// ---------------- bf16 GEMM: C[M,N] = A[M,K] @ W[N,K]^T (m97 structure) ------
template<int OUTF32>
__global__ __launch_bounds__(256) void gemm_bt(const unsigned short* __restrict__ A,
                                               const unsigned short* __restrict__ W,
                                               void* __restrict__ C, int M, int N, int K){
  __shared__ unsigned short As[128*32];
  __shared__ unsigned short Ws[128*32];
  const int tid = threadIdx.x;
  const int lane = tid & 63, wv = tid >> 6;
  const int tn = blockIdx.x, tm = blockIdx.y;
  const int wr = wv >> 1, wc = wv & 1;
  const int r = lane & 15, kq = lane >> 4;
  f32x4 acc[4][4];
  #pragma unroll
  for (int m=0;m<4;m++)
    #pragma unroll
    for (int n=0;n<4;n++) acc[m][n] = {0.f,0.f,0.f,0.f};
  const unsigned short* Ab = A + (size_t)tm*128*K;
  const unsigned short* Wb = W + (size_t)tn*128*K;
  for (int kt = 0; kt < K; kt += 32){
    #pragma unroll
    for (int i=0;i<2;i++){
      int ch = i*4 + wv;
      int o = (ch<<10) + lane*16;
      int row = o >> 6;
      int cole = (o & 63) >> 1;
      __builtin_amdgcn_global_load_lds(
        (const AS1 void*)(Ab + (size_t)row*K + kt + cole),
        (AS3 void*)((char*)As + (ch<<10)), 16, 0, 0);
      __builtin_amdgcn_global_load_lds(
        (const AS1 void*)(Wb + (size_t)row*K + kt + cole),
        (AS3 void*)((char*)Ws + (ch<<10)), 16, 0, 0);
    }
    __syncthreads();
    bf16x8 av[4], bv[4];
    #pragma unroll
    for (int m=0;m<4;m++) av[m] = *(const bf16x8*)&As[(wr*64 + m*16 + r)*32 + kq*8];
    #pragma unroll
    for (int n=0;n<4;n++) bv[n] = *(const bf16x8*)&Ws[(wc*64 + n*16 + r)*32 + kq*8];
    #pragma unroll
    for (int m=0;m<4;m++)
      #pragma unroll
      for (int n=0;n<4;n++)
        acc[m][n] = __builtin_amdgcn_mfma_f32_16x16x32_bf16(av[m], bv[n], acc[m][n], 0, 0, 0);
    __syncthreads();
  }
  #pragma unroll
  for (int m=0;m<4;m++)
    #pragma unroll
    for (int n=0;n<4;n++)
      #pragma unroll
      for (int j=0;j<4;j++){
        int gr = tm*128 + wr*64 + m*16 + kq*4 + j;
        int gc = tn*128 + wc*64 + n*16 + r;
        if (OUTF32) ((float*)C)[(size_t)gr*N + gc] = acc[m][n][j];
        else ((unsigned short*)C)[(size_t)gr*N + gc] = f2bf(acc[m][n][j]);
      }
}

// ---------------- causal GQA flash attention v2 ----------------
// 1D grid 1024 blocks, qt descending. 4 waves x 16 q rows. KVBLK=64.
// Ks linear [64 kv][16 ch of 16B], content chunk = ch ^ (kv&7)  (d-chunks)
// Vs linear [128 d][8 ch of 16B],  content chunk = ch ^ (d&7)   (pi-space kv-chunks)
__global__ __launch_bounds__(256) void attn_fwd2(const unsigned short* __restrict__ QKV,
                                                 const unsigned short* __restrict__ Vt,
                                                 unsigned short* __restrict__ AO){
  __shared__ unsigned short Ks[64*128];
  __shared__ unsigned short Vs[128*64];
  __shared__ unsigned short Pl[4][16][72];
  const int tid = threadIdx.x;
  const int lane = tid & 63, wv = tid >> 6;
  const int bid = blockIdx.x;
  const int h = bid & 31;
  const int qt = (S_LEN/64 - 1) - (bid >> 5);
  const int kvh = h >> 2;
  const int q0 = qt*64 + wv*16;
  const int r = lane & 15, kq = lane >> 4;
  const float scale = 0.08838834764831845f;
  const float L2E = 1.44269504088896f;

  bf16x8 qf[4];
  #pragma unroll
  for (int kc=0;kc<4;kc++)
    qf[kc] = *(const bf16x8*)&QKV[(size_t)(q0 + r)*QKVN + h*HDIM + kc*32 + kq*8];

  f32x4 oacc[8];
  #pragma unroll
  for (int d=0;d<8;d++) oacc[d] = {0.f,0.f,0.f,0.f};
  float mrow[4] = {-3e38f,-3e38f,-3e38f,-3e38f};
  float lsum[4] = {0.f,0.f,0.f,0.f};

  const unsigned short* Kbase = QKV + KOFS + kvh*HDIM;
  const unsigned short* Vbase = Vt + (size_t)kvh*HDIM*S_LEN;

  const int ntiles = qt + 1;
  for (int t=0;t<ntiles;t++){
    const int kv0 = t*64;
    __syncthreads();                       // prev tile's Ks/Vs reads done
    #pragma unroll
    for (int i=0;i<4;i++){                 // stage K: 1024 16B chunks
      int ci = (wv*4+i)*64 + lane;
      int kv = ci >> 4, ch = ci & 15;
      __builtin_amdgcn_global_load_lds(
        (const AS1 void*)(Kbase + (size_t)(kv0+kv)*QKVN + ((ch ^ (kv&7))*8)),
        (AS3 void*)((char*)Ks + (wv*4+i)*1024), 16, 0, 0);
    }
    #pragma unroll
    for (int i=0;i<4;i++){                 // stage V: 1024 16B chunks
      int ci = (wv*4+i)*64 + lane;
      int d = ci >> 3, ch = ci & 7;
      __builtin_amdgcn_global_load_lds(
        (const AS1 void*)(Vbase + (size_t)d*S_LEN + kv0 + ((ch ^ (d&7))*8)),
        (AS3 void*)((char*)Vs + (wv*4+i)*1024), 16, 0, 0);
    }
    __syncthreads();                       // staging complete (drains vmcnt)

    // QK^T : 4 kv-fragments x 4 k-chunks
    f32x4 s4[4];
    #pragma unroll
    for (int f=0;f<4;f++) s4[f] = {0.f,0.f,0.f,0.f};
    #pragma unroll
    for (int f=0;f<4;f++)
      #pragma unroll
      for (int kc=0;kc<4;kc++){
        bf16x8 kf = *(const bf16x8*)&Ks[(f*16+r)*128 + (((kc*4+kq) ^ (r&7))*8)];
        s4[f] = __builtin_amdgcn_mfma_f32_16x16x32_bf16(qf[kc], kf, s4[f], 0, 0, 0);
      }

    // online softmax, defer-max (THR=8)
    float sv[4][4]; float mx4[4];
    #pragma unroll
    for (int j=0;j<4;j++){
      int qg = q0 + kq*4 + j;
      #pragma unroll
      for (int f=0;f<4;f++)
        sv[j][f] = (kv0 + f*16 + r <= qg) ? s4[f][j]*scale : -3e38f;
      float mx = fmaxf(fmaxf(sv[j][0], sv[j][1]), fmaxf(sv[j][2], sv[j][3]));
      #pragma unroll
      for (int d=1; d<16; d<<=1) mx = fmaxf(mx, __shfl_xor(mx, d));
      mx4[j] = mx;
    }
    float need = fmaxf(fmaxf(mx4[0]-mrow[0], mx4[1]-mrow[1]),
                       fmaxf(mx4[2]-mrow[2], mx4[3]-mrow[3]));
    const bool defer = __all(need <= 8.0f);
    #pragma unroll
    for (int j=0;j<4;j++){
      float mnew = defer ? mrow[j] : fmaxf(mrow[j], mx4[j]);
      float alpha = defer ? 1.0f : exp2f((mrow[j]-mnew)*L2E);
      mrow[j] = mnew;
      float p0 = exp2f((sv[j][0]-mnew)*L2E);
      float p1 = exp2f((sv[j][1]-mnew)*L2E);
      float p2 = exp2f((sv[j][2]-mnew)*L2E);
      float p3 = exp2f((sv[j][3]-mnew)*L2E);
      float rs = (p0+p1)+(p2+p3);
      #pragma unroll
      for (int d=1; d<16; d<<=1) rs += __shfl_xor(rs, d);
      lsum[j] = lsum[j]*alpha + rs;
      if (!defer){
        #pragma unroll
        for (int df=0;df<8;df++) oacc[df][j] *= alpha;
      }
      // P store: pi-position r*4+f -> packed b64, conflict-free
      bf16x4 pk; pk[0]=(short)f2bf(p0); pk[1]=(short)f2bf(p1); pk[2]=(short)f2bf(p2); pk[3]=(short)f2bf(p3);
      *(bf16x4*)&Pl[wv][kq*4+j][r*4] = pk;
    }

    // PV: A = P (pi-space), B = Vs (pi-space)
    bf16x8 pa0 = *(const bf16x8*)&Pl[wv][r][kq*8];
    bf16x8 pa1 = *(const bf16x8*)&Pl[wv][r][32 + kq*8];
    #pragma unroll
    for (int df=0;df<8;df++){
      int d = df*16 + r;
      bf16x8 v0 = *(const bf16x8*)&Vs[d*64 + ((kq ^ (r&7))*8)];
      bf16x8 v1 = *(const bf16x8*)&Vs[d*64 + (((4+kq) ^ (r&7))*8)];
      oacc[df] = __builtin_amdgcn_mfma_f32_16x16x32_bf16(pa0, v0, oacc[df], 0, 0, 0);
      oacc[df] = __builtin_amdgcn_mfma_f32_16x16x32_bf16(pa1, v1, oacc[df], 0, 0, 0);
    }
  }

  #pragma unroll
  for (int df=0;df<8;df++)
    #pragma unroll
    for (int j=0;j<4;j++){
      int qg = q0 + kq*4 + j;
      AO[(size_t)qg*HID + h*HDIM + df*16 + r] = f2bf(oacc[df][j] / lsum[j]);
    }
}

// ---------------- launch ----------------
extern "C" void kernel_launch(void* const* d_in, const int* in_sizes, int n_in,
                              void* d_out, int out_size, void* d_ws, size_t ws_size,
                              hipStream_t stream){
  (void)in_sizes; (void)n_in; (void)out_size; (void)ws_size;
  const float* hs = (const float*)d_in[0];
  const float* Wq = (const float*)d_in[1];
  const float* Wk = (const float*)d_in[2];
  const float* Wv = (const float*)d_in[3];
  const float* Wo = (const float*)d_in[4];
  float* out = (float*)d_out;
  char* ws = (char*)d_ws;
  size_t off = 0;
  auto alloc = [&](size_t bytes)->void*{ void* p = ws + off; off += (bytes + 255) & ~(size_t)255; return p; };

  unsigned short* Hb    = (unsigned short*)alloc((size_t)S_LEN*HID*2);
  unsigned short* Wqkvb = (unsigned short*)alloc((size_t)QKVN*HID*2);
  unsigned short* Wob   = (unsigned short*)alloc((size_t)HID*HID*2);
  unsigned short* QKVb  = (unsigned short*)alloc((size_t)S_LEN*QKVN*2);
  unsigned short* AOb   = (unsigned short*)alloc((size_t)S_LEN*HID*2);
  unsigned short* Vtb   = (unsigned short*)alloc((size_t)NKVH*HDIM*S_LEN*2);
  float* cosT = (float*)alloc((size_t)S_LEN*64*4);
  float* sinT = (float*)alloc((size_t)S_LEN*64*4);

  auto cvt = [&](const float* s, unsigned short* d, size_t n){
    int n4 = (int)(n/4);
    cvt_f32_bf16<<<(n4+255)/256, 256, 0, stream>>>(s, d, n4);
  };
  cvt(hs, Hb,  (size_t)S_LEN*HID);
  cvt(Wq, Wqkvb,                       (size_t)HID*HID);
  cvt(Wk, Wqkvb + (size_t)KOFS*HID,    (size_t)NKVH*HDIM*HID);
  cvt(Wv, Wqkvb + (size_t)VOFS*HID,    (size_t)NKVH*HDIM*HID);
  cvt(Wo, Wob, (size_t)HID*HID);
  rope_table<<<(S_LEN*64)/256, 256, 0, stream>>>(cosT, sinT);

  gemm_bt<0><<<dim3(QKVN/128, S_LEN/128), 256, 0, stream>>>(Hb, Wqkvb, QKVb, S_LEN, QKVN, HID);

  transpose_v<<<dim3(S_LEN/64, NKVH), 256, 0, stream>>>(QKVb, Vtb);

  int totQ = S_LEN*NHEADS*64;
  rope_apply<<<(totQ+255)/256, 256, 0, stream>>>(QKVb, cosT, sinT, NHEADS, QKVN, 0,    totQ);
  int totK = S_LEN*NKVH*64;
  rope_apply<<<(totK+255)/256, 256, 0, stream>>>(QKVb, cosT, sinT, NKVH,   QKVN, KOFS, totK);

  attn_fwd2<<<dim3(1024), 256, 0, stream>>>(QKVb, Vtb, AOb);

  gemm_bt<1><<<dim3(HID/128, S_LEN/128), 256, 0, stream>>>(AOb, Wob, out, S_LEN, HID, HID);
}

// Round 3
// 393.534 us; speedup vs baseline: 1.7090x; 1.0654x over previous
//
#include <hip/hip_runtime.h>

typedef __attribute__((ext_vector_type(8))) short bf16x8;
typedef __attribute__((ext_vector_type(4))) short bf16x4;
typedef __attribute__((ext_vector_type(4))) float f32x4;

#define S_LEN  2048
#define HID    4096
#define NHEADS 32
#define NKVH   8
#define HDIM   128
#define QKVN   (HID + 2*NKVH*HDIM)   // 6144
#define KOFS   HID
#define VOFS   (HID + NKVH*HDIM)

#define AS1 __attribute__((address_space(1)))
#define AS3 __attribute__((address_space(3)))

__device__ __forceinline__ unsigned short f2bf(float f){
  unsigned int x = __float_as_uint(f);
  x += 0x7fffu + ((x >> 16) & 1u);
  return (unsigned short)(x >> 16);
}
__device__ __forceinline__ float bf2f(unsigned short h){
  return __uint_as_float(((unsigned int)h) << 16);
}

// ---------------- fp32 -> bf16 conversion ----------------
__global__ void cvt_f32_bf16(const float* __restrict__ src, unsigned short* __restrict__ dst, int n4){
  int i = blockIdx.x * blockDim.x + threadIdx.x;
  if (i < n4){
    float4 v = *(const float4*)(src + (size_t)i*4);
    ushort4 o;
    o.x = f2bf(v.x); o.y = f2bf(v.y); o.z = f2bf(v.z); o.w = f2bf(v.w);
    *(ushort4*)(dst + (size_t)i*4) = o;
  }
}

// ---------------- RoPE ----------------
__global__ void rope_table(float* __restrict__ cosT, float* __restrict__ sinT){
  int idx = blockIdx.x * blockDim.x + threadIdx.x;
  int s = idx >> 6, i = idx & 63;
  float inv = expf(-(float)i * (13.122363377404329f / 64.0f));
  float a = (float)s * inv;
  cosT[idx] = cosf(a);
  sinT[idx] = sinf(a);
}

__global__ void rope_apply(unsigned short* __restrict__ X, const float* __restrict__ cosT,
                           const float* __restrict__ sinT, int nh, int rowstr, int colofs, int total){
  int idx = blockIdx.x * blockDim.x + threadIdx.x;
  if (idx >= total) return;
  int i = idx & 63;
  int h = (idx >> 6) % nh;
  int s = idx / (64*nh);
  size_t base = (size_t)s*rowstr + colofs + h*HDIM + i;
  float x0 = bf2f(X[base]), x1 = bf2f(X[base+64]);
  float c = cosT[(s<<6)|i], sn = sinT[(s<<6)|i];
  X[base]    = f2bf(x0*c - x1*sn);
  X[base+64] = f2bf(x1*c + x0*sn);
}

// ---------------- V transpose: Vt[kvh][d][s], s pi-permuted within 64-blocks ----
__global__ __launch_bounds__(256) void transpose_v(const unsigned short* __restrict__ QKV,
                                                   unsigned short* __restrict__ Vt){
  __shared__ unsigned short T[64][130];
  const int qt = blockIdx.x, kvh = blockIdx.y;
  const int tid = threadIdx.x;
  #pragma unroll
  for (int i=0;i<4;i++){
    int c = tid + i*256;
    int sl = c >> 4;
    int d0 = (c & 15) * 8;
    bf16x8 v = *(const bf16x8*)&QKV[(size_t)(qt*64+sl)*QKVN + VOFS + kvh*HDIM + d0];
    #pragma unroll
    for (int j=0;j<8;j++) T[sl][d0+j] = (unsigned short)v[j];
  }
  __syncthreads();
  #pragma unroll
  for (int i=0;i<4;i++){
    int c = tid + i*256;
    int d = c >> 3;
    int p0 = (c & 7) * 8;
    bf16x8 o;
    #pragma unroll
    for (int j=0;j<8;j++){
      int p = p0 + j;
      int s_nat = (p >> 2) + (p & 3) * 16;
      o[j] = (short)T[s_nat][d];
    }
    *(bf16x8*)&Vt[((size_t)kvh*HDIM + d)*S_LEN + qt*64 + p0] = o;
  }
}

// ---------------- deep-pipelined bf16 GEMM: C[M,N] = A[M,K] @ W[N,K]^T --------
// BM=256, BK=32, 8 waves (2Mx4N), 4-deep LDS ring, 2 phases/K-tile,
// counted vmcnt (T4), setprio around MFMA (T5), chunk-XOR swizzle (T2, rule 21).
template<int BN, int OUTF32>
__global__ __launch_bounds__(512, 2) void gemm8p(const unsigned short* __restrict__ A,
                                                 const unsigned short* __restrict__ W,
                                                 void* __restrict__ C, int M, int N, int K){
  constexpr int NF  = BN / 64;          // per-wave N-fragments (4 or 2)
  constexpr int LB  = (BN * 64) / 8192; // B loads per tile (2 or 1)
  constexpr int LPT = 2 + LB;           // loads per tile
  constexpr int BSZ = BN * 64;          // B tile bytes
  __shared__ char lds_raw[4*16384 + 4*BSZ];
  unsigned short* ldsu = (unsigned short*)lds_raw;

  const int tid = threadIdx.x;
  const int lane = tid & 63, wv = tid >> 6;
  const int wm = wv >> 2, wn = wv & 3;
  const int r = lane & 15, kq = lane >> 4;
  const int tn = blockIdx.x, tm = blockIdx.y;
  const unsigned short* Ab = A + (size_t)tm*256*K;
  const unsigned short* Wb = W + (size_t)tn*BN*K;

  f32x4 acc[8][NF];
  #pragma unroll
  for (int m=0;m<8;m++)
    #pragma unroll
    for (int n=0;n<NF;n++) acc[m][n] = {0.f,0.f,0.f,0.f};

  auto stageA = [&](int buf, int kt){
    #pragma unroll
    for (int l=0;l<2;l++){
      int c = l*512 + wv*64 + lane;
      int row = c >> 2, kcp = c & 3;
      __builtin_amdgcn_global_load_lds(
        (const AS1 void*)(Ab + (size_t)row*K + kt + ((kcp ^ (row&3))*8)),
        (AS3 void*)(lds_raw + buf*16384 + (l*512 + wv*64)*16), 16, 0, 0);
    }
  };
  auto stageB = [&](int buf, int kt){
    #pragma unroll
    for (int l=0;l<LB;l++){
      int c = l*512 + wv*64 + lane;
      int row = c >> 2, kcp = c & 3;
      __builtin_amdgcn_global_load_lds(
        (const AS1 void*)(Wb + (size_t)row*K + kt + ((kcp ^ (row&3))*8)),
        (AS3 void*)(lds_raw + 4*16384 + buf*BSZ + (l*512 + wv*64)*16), 16, 0, 0);
    }
  };
  auto rdA = [&](int buf, int m)->bf16x8 {
    int row = wm*128 + m*16 + r;
    return *(const bf16x8*)&ldsu[buf*8192 + row*32 + ((kq ^ (r&3))*8)];
  };
  auto rdB = [&](int buf, int n)->bf16x8 {
    int row = wn*(BN/4) + n*16 + r;
    return *(const bf16x8*)&ldsu[4*8192 + buf*(BSZ/2) + row*32 + ((kq ^ (r&3))*8)];
  };

  const int nt = K / 32;
  // prologue: stage tiles 0,1,2; wait until tile0 landed (2 tiles in flight)
  stageA(0, 0);  stageB(0, 0);
  stageA(1, 32); stageB(1, 32);
  stageA(2, 64); stageB(2, 64);
  if constexpr (LPT == 4) { asm volatile("s_waitcnt vmcnt(8)" ::: "memory"); }
  else                    { asm volatile("s_waitcnt vmcnt(6)" ::: "memory"); }
  __builtin_amdgcn_s_barrier();

  for (int t = 0; t < nt; ++t){
    const int buf = t & 3;
    const int kt3 = (t+3)*32;
    // ---- phase A: M-frags 0..3, all N-frags; stage A-half of tile t+3
    bf16x8 a0 = rdA(buf,0), a1 = rdA(buf,1), a2 = rdA(buf,2), a3 = rdA(buf,3);
    bf16x8 bfr[NF];
    #pragma unroll
    for (int n=0;n<NF;n++) bfr[n] = rdB(buf, n);
    if (t + 3 < nt) stageA((t+3)&3, kt3);
    __builtin_amdgcn_s_barrier();
    asm volatile("s_waitcnt lgkmcnt(0)" ::: "memory");
    __builtin_amdgcn_s_setprio(1);
    #pragma unroll
    for (int n=0;n<NF;n++){
      acc[0][n] = __builtin_amdgcn_mfma_f32_16x16x32_bf16(a0, bfr[n], acc[0][n], 0, 0, 0);
      acc[1][n] = __builtin_amdgcn_mfma_f32_16x16x32_bf16(a1, bfr[n], acc[1][n], 0, 0, 0);
      acc[2][n] = __builtin_amdgcn_mfma_f32_16x16x32_bf16(a2, bfr[n], acc[2][n], 0, 0, 0);
      acc[3][n] = __builtin_amdgcn_mfma_f32_16x16x32_bf16(a3, bfr[n], acc[3][n], 0, 0, 0);
    }
    __builtin_amdgcn_s_setprio(0);
    __builtin_amdgcn_s_barrier();
    // ---- phase B: M-frags 4..7 (B-frags reused from regs); stage B-half of t+3
    a0 = rdA(buf,4); a1 = rdA(buf,5); a2 = rdA(buf,6); a3 = rdA(buf,7);
    if (t + 3 < nt) stageB((t+3)&3, kt3);
    __builtin_amdgcn_s_barrier();
    asm volatile("s_waitcnt lgkmcnt(0)" ::: "memory");
    __builtin_amdgcn_s_setprio(1);
    #pragma unroll
    for (int n=0;n<NF;n++){
      acc[4][n] = __builtin_amdgcn_mfma_f32_16x16x32_bf16(a0, bfr[n], acc[4][n], 0, 0, 0);
      acc[5][n] = __builtin_amdgcn_mfma_f32_16x16x32_bf16(a1, bfr[n], acc[5][n], 0, 0, 0);
      acc[6][n] = __builtin_amdgcn_mfma_f32_16x16x32_bf16(a2, bfr[n], acc[6][n], 0, 0, 0);
      acc[7][n] = __builtin_amdgcn_mfma_f32_16x16x32_bf16(a3, bfr[n], acc[7][n], 0, 0, 0);
    }
    __builtin_amdgcn_s_setprio(0);
    // counted vmcnt once per K-tile: keep 2 tiles of loads in flight
    if (t + 3 < nt){
      if constexpr (LPT == 4) { asm volatile("s_waitcnt vmcnt(8)" ::: "memory"); }
      else                    { asm volatile("s_waitcnt vmcnt(6)" ::: "memory"); }
    } else if (t + 2 < nt){
      if constexpr (LPT == 4) { asm volatile("s_waitcnt vmcnt(4)" ::: "memory"); }
      else                    { asm volatile("s_waitcnt vmcnt(3)" ::: "memory"); }
    } else if (t + 1 < nt){
      asm volatile("s_waitcnt vmcnt(0)" ::: "memory");
    }
    __builtin_amdgcn_s_barrier();
  }

  #pragma unroll
  for (int m=0;m<8;m++)
    #pragma unroll
    for (int n=0;n<NF;n++)
      #pragma unroll
      for (int j=0;j<4;j++){
        int gr = tm*256 + wm*128 + m*16 + kq*4 + j;
        int gc = tn*BN + wn*(BN/4) + n*16 + r;
        if (OUTF32) ((float*)C)[(size_t)gr*N + gc] = acc[m][n][j];
        else ((unsigned short*)C)[(size_t)gr*N + gc] = f2bf(acc[m][n][j]);
      }
}

// ---------------- causal GQA flash attention v2 ----------------
__global__ __launch_bounds__(256) void attn_fwd2(const unsigned short* __restrict__ QKV,
                                                 const unsigned short* __restrict__ Vt,
                                                 unsigned short* __restrict__ AO){
  __shared__ unsigned short Ks[64*128];
  __shared__ unsigned short Vs[128*64];
  __shared__ unsigned short Pl[4][16][72];
  const int tid = threadIdx.x;
  const int lane = tid & 63, wv = tid >> 6;
  const int bid = blockIdx.x;
  const int h = bid & 31;
  const int qt = (S_LEN/64 - 1) - (bid >> 5);
  const int kvh = h >> 2;
  const int q0 = qt*64 + wv*16;
  const int r = lane & 15, kq = lane >> 4;
  const float scale = 0.08838834764831845f;
  const float L2E = 1.44269504088896f;

  bf16x8 qf[4];
  #pragma unroll
  for (int kc=0;kc<4;kc++)
    qf[kc] = *(const bf16x8*)&QKV[(size_t)(q0 + r)*QKVN + h*HDIM + kc*32 + kq*8];

  f32x4 oacc[8];
  #pragma unroll
  for (int d=0;d<8;d++) oacc[d] = {0.f,0.f,0.f,0.f};
  float mrow[4] = {-3e38f,-3e38f,-3e38f,-3e38f};
  float lsum[4] = {0.f,0.f,0.f,0.f};

  const unsigned short* Kbase = QKV + KOFS + kvh*HDIM;
  const unsigned short* Vbase = Vt + (size_t)kvh*HDIM*S_LEN;

  const int ntiles = qt + 1;
  for (int t=0;t<ntiles;t++){
    const int kv0 = t*64;
    __syncthreads();
    #pragma unroll
    for (int i=0;i<4;i++){
      int ci = (wv*4+i)*64 + lane;
      int kv = ci >> 4, ch = ci & 15;
      __builtin_amdgcn_global_load_lds(
        (const AS1 void*)(Kbase + (size_t)(kv0+kv)*QKVN + ((ch ^ (kv&7))*8)),
        (AS3 void*)((char*)Ks + (wv*4+i)*1024), 16, 0, 0);
    }
    #pragma unroll
    for (int i=0;i<4;i++){
      int ci = (wv*4+i)*64 + lane;
      int d = ci >> 3, ch = ci & 7;
      __builtin_amdgcn_global_load_lds(
        (const AS1 void*)(Vbase + (size_t)d*S_LEN + kv0 + ((ch ^ (d&7))*8)),
        (AS3 void*)((char*)Vs + (wv*4+i)*1024), 16, 0, 0);
    }
    __syncthreads();

    f32x4 s4[4];
    #pragma unroll
    for (int f=0;f<4;f++) s4[f] = {0.f,0.f,0.f,0.f};
    #pragma unroll
    for (int f=0;f<4;f++)
      #pragma unroll
      for (int kc=0;kc<4;kc++){
        bf16x8 kf = *(const bf16x8*)&Ks[(f*16+r)*128 + (((kc*4+kq) ^ (r&7))*8)];
        s4[f] = __builtin_amdgcn_mfma_f32_16x16x32_bf16(qf[kc], kf, s4[f], 0, 0, 0);
      }

    float sv[4][4]; float mx4[4];
    #pragma unroll
    for (int j=0;j<4;j++){
      int qg = q0 + kq*4 + j;
      #pragma unroll
      for (int f=0;f<4;f++)
        sv[j][f] = (kv0 + f*16 + r <= qg) ? s4[f][j]*scale : -3e38f;
      float mx = fmaxf(fmaxf(sv[j][0], sv[j][1]), fmaxf(sv[j][2], sv[j][3]));
      #pragma unroll
      for (int d=1; d<16; d<<=1) mx = fmaxf(mx, __shfl_xor(mx, d));
      mx4[j] = mx;
    }
    float need = fmaxf(fmaxf(mx4[0]-mrow[0], mx4[1]-mrow[1]),
                       fmaxf(mx4[2]-mrow[2], mx4[3]-mrow[3]));
    const bool defer = __all(need <= 8.0f);
    #pragma unroll
    for (int j=0;j<4;j++){
      float mnew = defer ? mrow[j] : fmaxf(mrow[j], mx4[j]);
      float alpha = defer ? 1.0f : exp2f((mrow[j]-mnew)*L2E);
      mrow[j] = mnew;
      float p0 = exp2f((sv[j][0]-mnew)*L2E);
      float p1 = exp2f((sv[j][1]-mnew)*L2E);
      float p2 = exp2f((sv[j][2]-mnew)*L2E);
      float p3 = exp2f((sv[j][3]-mnew)*L2E);
      float rs = (p0+p1)+(p2+p3);
      #pragma unroll
      for (int d=1; d<16; d<<=1) rs += __shfl_xor(rs, d);
      lsum[j] = lsum[j]*alpha + rs;
      if (!defer){
        #pragma unroll
        for (int df=0;df<8;df++) oacc[df][j] *= alpha;
      }
      bf16x4 pk; pk[0]=(short)f2bf(p0); pk[1]=(short)f2bf(p1); pk[2]=(short)f2bf(p2); pk[3]=(short)f2bf(p3);
      *(bf16x4*)&Pl[wv][kq*4+j][r*4] = pk;
    }

    bf16x8 pa0 = *(const bf16x8*)&Pl[wv][r][kq*8];
    bf16x8 pa1 = *(const bf16x8*)&Pl[wv][r][32 + kq*8];
    #pragma unroll
    for (int df=0;df<8;df++){
      int d = df*16 + r;
      bf16x8 v0 = *(const bf16x8*)&Vs[d*64 + ((kq ^ (r&7))*8)];
      bf16x8 v1 = *(const bf16x8*)&Vs[d*64 + (((4+kq) ^ (r&7))*8)];
      oacc[df] = __builtin_amdgcn_mfma_f32_16x16x32_bf16(pa0, v0, oacc[df], 0, 0, 0);
      oacc[df] = __builtin_amdgcn_mfma_f32_16x16x32_bf16(pa1, v1, oacc[df], 0, 0, 0);
    }
  }

  #pragma unroll
  for (int df=0;df<8;df++)
    #pragma unroll
    for (int j=0;j<4;j++){
      int qg = q0 + kq*4 + j;
      AO[(size_t)qg*HID + h*HDIM + df*16 + r] = f2bf(oacc[df][j] / lsum[j]);
    }
}

// ---------------- launch ----------------
extern "C" void kernel_launch(void* const* d_in, const int* in_sizes, int n_in,
                              void* d_out, int out_size, void* d_ws, size_t ws_size,
                              hipStream_t stream){
  (void)in_sizes; (void)n_in; (void)out_size; (void)ws_size;
  const float* hs = (const float*)d_in[0];
  const float* Wq = (const float*)d_in[1];
  const float* Wk = (const float*)d_in[2];
  const float* Wv = (const float*)d_in[3];
  const float* Wo = (const float*)d_in[4];
  float* out = (float*)d_out;
  char* ws = (char*)d_ws;
  size_t off = 0;
  auto alloc = [&](size_t bytes)->void*{ void* p = ws + off; off += (bytes + 255) & ~(size_t)255; return p; };

  unsigned short* Hb    = (unsigned short*)alloc((size_t)S_LEN*HID*2);
  unsigned short* Wqkvb = (unsigned short*)alloc((size_t)QKVN*HID*2);
  unsigned short* Wob   = (unsigned short*)alloc((size_t)HID*HID*2);
  unsigned short* QKVb  = (unsigned short*)alloc((size_t)S_LEN*QKVN*2);
  unsigned short* AOb   = (unsigned short*)alloc((size_t)S_LEN*HID*2);
  unsigned short* Vtb   = (unsigned short*)alloc((size_t)NKVH*HDIM*S_LEN*2);
  float* cosT = (float*)alloc((size_t)S_LEN*64*4);
  float* sinT = (float*)alloc((size_t)S_LEN*64*4);

  auto cvt = [&](const float* s, unsigned short* d, size_t n){
    int n4 = (int)(n/4);
    cvt_f32_bf16<<<(n4+255)/256, 256, 0, stream>>>(s, d, n4);
  };
  cvt(hs, Hb,  (size_t)S_LEN*HID);
  cvt(Wq, Wqkvb,                       (size_t)HID*HID);
  cvt(Wk, Wqkvb + (size_t)KOFS*HID,    (size_t)NKVH*HDIM*HID);
  cvt(Wv, Wqkvb + (size_t)VOFS*HID,    (size_t)NKVH*HDIM*HID);
  cvt(Wo, Wob, (size_t)HID*HID);
  rope_table<<<(S_LEN*64)/256, 256, 0, stream>>>(cosT, sinT);

  // fused QKV projection: [2048,6144] = Hb @ Wqkv^T   (BM=256,BN=256 -> 192 blocks)
  gemm8p<256,0><<<dim3(QKVN/256, S_LEN/256), 512, 0, stream>>>(Hb, Wqkvb, QKVb, S_LEN, QKVN, HID);

  transpose_v<<<dim3(S_LEN/64, NKVH), 256, 0, stream>>>(QKVb, Vtb);

  int totQ = S_LEN*NHEADS*64;
  rope_apply<<<(totQ+255)/256, 256, 0, stream>>>(QKVb, cosT, sinT, NHEADS, QKVN, 0,    totQ);
  int totK = S_LEN*NKVH*64;
  rope_apply<<<(totK+255)/256, 256, 0, stream>>>(QKVb, cosT, sinT, NKVH,   QKVN, KOFS, totK);

  attn_fwd2<<<dim3(1024), 256, 0, stream>>>(QKVb, Vtb, AOb);

  // output projection (BM=256,BN=128 -> 256 blocks = full machine), fp32 epilogue
  gemm8p<128,1><<<dim3(HID/128, S_LEN/256), 512, 0, stream>>>(AOb, Wob, out, S_LEN, HID, HID);
}

// Round 4
// 342.368 us; speedup vs baseline: 1.9644x; 1.1494x over previous
//
#include <hip/hip_runtime.h>

typedef __attribute__((ext_vector_type(8))) short bf16x8;
typedef __attribute__((ext_vector_type(4))) short bf16x4;
typedef __attribute__((ext_vector_type(4))) float f32x4;

#define S_LEN  2048
#define HID    4096
#define NHEADS 32
#define NKVH   8
#define HDIM   128
#define QKVN   (HID + 2*NKVH*HDIM)   // 6144
#define KOFS   HID
#define VOFS   (HID + NKVH*HDIM)

#define AS1 __attribute__((address_space(1)))
#define AS3 __attribute__((address_space(3)))

__device__ __forceinline__ unsigned short f2bf(float f){
  unsigned int x = __float_as_uint(f);
  x += 0x7fffu + ((x >> 16) & 1u);
  return (unsigned short)(x >> 16);
}
__device__ __forceinline__ float bf2f(unsigned short h){
  return __uint_as_float(((unsigned int)h) << 16);
}

// ---------------- fp32 -> bf16 conversion ----------------
__global__ void cvt_f32_bf16(const float* __restrict__ src, unsigned short* __restrict__ dst, int n4){
  int i = blockIdx.x * blockDim.x + threadIdx.x;
  if (i < n4){
    float4 v = *(const float4*)(src + (size_t)i*4);
    ushort4 o;
    o.x = f2bf(v.x); o.y = f2bf(v.y); o.z = f2bf(v.z); o.w = f2bf(v.w);
    *(ushort4*)(dst + (size_t)i*4) = o;
  }
}

// ---------------- RoPE ----------------
__global__ void rope_table(float* __restrict__ cosT, float* __restrict__ sinT){
  int idx = blockIdx.x * blockDim.x + threadIdx.x;
  int s = idx >> 6, i = idx & 63;
  float inv = expf(-(float)i * (13.122363377404329f / 64.0f));
  float a = (float)s * inv;
  cosT[idx] = cosf(a);
  sinT[idx] = sinf(a);
}

__global__ void rope_apply(unsigned short* __restrict__ X, const float* __restrict__ cosT,
                           const float* __restrict__ sinT, int nh, int rowstr, int colofs, int total){
  int idx = blockIdx.x * blockDim.x + threadIdx.x;
  if (idx >= total) return;
  int i = idx & 63;
  int h = (idx >> 6) % nh;
  int s = idx / (64*nh);
  size_t base = (size_t)s*rowstr + colofs + h*HDIM + i;
  float x0 = bf2f(X[base]), x1 = bf2f(X[base+64]);
  float c = cosT[(s<<6)|i], sn = sinT[(s<<6)|i];
  X[base]    = f2bf(x0*c - x1*sn);
  X[base+64] = f2bf(x1*c + x0*sn);
}

// ---------------- V transpose: Vt[kvh][d][s], s pi-permuted within 64-blocks ----
__global__ __launch_bounds__(256) void transpose_v(const unsigned short* __restrict__ QKV,
                                                   unsigned short* __restrict__ Vt){
  __shared__ unsigned short T[64][130];
  const int qt = blockIdx.x, kvh = blockIdx.y;
  const int tid = threadIdx.x;
  #pragma unroll
  for (int i=0;i<4;i++){
    int c = tid + i*256;
    int sl = c >> 4;
    int d0 = (c & 15) * 8;
    bf16x8 v = *(const bf16x8*)&QKV[(size_t)(qt*64+sl)*QKVN + VOFS + kvh*HDIM + d0];
    #pragma unroll
    for (int j=0;j<8;j++) T[sl][d0+j] = (unsigned short)v[j];
  }
  __syncthreads();
  #pragma unroll
  for (int i=0;i<4;i++){
    int c = tid + i*256;
    int d = c >> 3;
    int p0 = (c & 7) * 8;
    bf16x8 o;
    #pragma unroll
    for (int j=0;j<8;j++){
      int p = p0 + j;
      int s_nat = (p >> 2) + (p & 3) * 16;
      o[j] = (short)T[s_nat][d];
    }
    *(bf16x8*)&Vt[((size_t)kvh*HDIM + d)*S_LEN + qt*64 + p0] = o;
  }
}

// ---- free-run bf16 GEMM v3: C[M,N] = A[M,K] @ W[N,K]^T -------------------
// BK=64 (128B rows), st_16x32 swizzle (ch ^= (row>>1)&2) on gload-source and
// ds_read (rule 21). Double-buffered; ONE barrier + ONE vmcnt(0) per K-tile;
// interior is free-running (compiler overlaps LDS reads and MFMA across waves).
// 8 waves 2Mx4N.
template<int BM, int BN, int OUTF32>
__global__ __launch_bounds__(512, 2) void gemm_fr(const unsigned short* __restrict__ A,
                                                  const unsigned short* __restrict__ W,
                                                  void* __restrict__ C, int M, int N, int K){
  constexpr int MF = BM/32;            // m-frags per wave
  constexpr int NF = BN/64;            // n-frags per wave
  constexpr int LA = BM/64;            // A gloads per thread per tile
  constexpr int LB = BN/64;            // B gloads per thread per tile
  constexpr int ABYTES = BM*128;
  constexpr int BBYTES = BN*128;
  __shared__ char lds_raw[2*ABYTES + 2*BBYTES];

  const int tid = threadIdx.x;
  const int lane = tid & 63, wv = tid >> 6;
  const int wm = wv >> 2, wn = wv & 3;
  const int r = lane & 15, kq = lane >> 4;
  const int tn = blockIdx.x, tm = blockIdx.y;
  const unsigned short* Ab = A + (size_t)tm*BM*K;
  const unsigned short* Wb = W + (size_t)tn*BN*K;

  f32x4 acc[MF][NF];
  #pragma unroll
  for (int m=0;m<MF;m++)
    #pragma unroll
    for (int n=0;n<NF;n++) acc[m][n] = {0.f,0.f,0.f,0.f};

  auto stage = [&](int buf, int kt){
    #pragma unroll
    for (int l=0;l<LA;l++){
      int c = l*512 + tid;
      int row = c >> 3, ch = c & 7;
      __builtin_amdgcn_global_load_lds(
        (const AS1 void*)(Ab + (size_t)row*K + kt + ((ch ^ ((row>>1)&2))*8)),
        (AS3 void*)(lds_raw + buf*ABYTES + (l*512 + wv*64)*16), 16, 0, 0);
    }
    #pragma unroll
    for (int l=0;l<LB;l++){
      int c = l*512 + tid;
      int row = c >> 3, ch = c & 7;
      __builtin_amdgcn_global_load_lds(
        (const AS1 void*)(Wb + (size_t)row*K + kt + ((ch ^ ((row>>1)&2))*8)),
        (AS3 void*)(lds_raw + 2*ABYTES + buf*BBYTES + (l*512 + wv*64)*16), 16, 0, 0);
    }
  };
  auto rdA = [&](int buf, int m, int kh)->bf16x8 {
    int row = wm*(BM/2) + m*16 + r;
    int ch = (kh*4 + kq) ^ ((r>>1)&2);
    return *(const bf16x8*)(lds_raw + buf*ABYTES + row*128 + ch*16);
  };
  auto rdB = [&](int buf, int n, int kh)->bf16x8 {
    int row = wn*(BN/4) + n*16 + r;
    int ch = (kh*4 + kq) ^ ((r>>1)&2);
    return *(const bf16x8*)(lds_raw + 2*ABYTES + buf*BBYTES + row*128 + ch*16);
  };

  const int nt = K/64;
  stage(0, 0);
  for (int t=0; t<nt; ++t){
    asm volatile("s_waitcnt vmcnt(0)" ::: "memory");  // own staging for tile t landed
    __builtin_amdgcn_s_barrier();                     // everyone's staging landed; prev reads done
    if (t+1 < nt) stage((t+1)&1, (t+1)*64);
    const int buf = t & 1;
    #pragma unroll
    for (int kh=0; kh<2; ++kh){
      bf16x8 av[MF], bv[NF];
      #pragma unroll
      for (int m=0;m<MF;m++) av[m] = rdA(buf, m, kh);
      #pragma unroll
      for (int n=0;n<NF;n++) bv[n] = rdB(buf, n, kh);
      #pragma unroll
      for (int m=0;m<MF;m++)
        #pragma unroll
        for (int n=0;n<NF;n++)
          acc[m][n] = __builtin_amdgcn_mfma_f32_16x16x32_bf16(av[m], bv[n], acc[m][n], 0, 0, 0);
    }
  }

  #pragma unroll
  for (int m=0;m<MF;m++)
    #pragma unroll
    for (int n=0;n<NF;n++)
      #pragma unroll
      for (int j=0;j<4;j++){
        int gr = tm*BM + wm*(BM/2) + m*16 + kq*4 + j;
        int gc = tn*BN + wn*(BN/4) + n*16 + r;
        if (OUTF32) ((float*)C)[(size_t)gr*N + gc] = acc[m][n][j];
        else ((unsigned short*)C)[(size_t)gr*N + gc] = f2bf(acc[m][n][j]);
      }
}

// ---------------- causal GQA flash attention v2 ----------------
__global__ __launch_bounds__(256) void attn_fwd2(const unsigned short* __restrict__ QKV,
                                                 const unsigned short* __restrict__ Vt,
                                                 unsigned short* __restrict__ AO){
  __shared__ unsigned short Ks[64*128];
  __shared__ unsigned short Vs[128*64];
  __shared__ unsigned short Pl[4][16][72];
  const int tid = threadIdx.x;
  const int lane = tid & 63, wv = tid >> 6;
  const int bid = blockIdx.x;
  const int h = bid & 31;
  const int qt = (S_LEN/64 - 1) - (bid >> 5);
  const int kvh = h >> 2;
  const int q0 = qt*64 + wv*16;
  const int r = lane & 15, kq = lane >> 4;
  const float scale = 0.08838834764831845f;
  const float L2E = 1.44269504088896f;

  bf16x8 qf[4];
  #pragma unroll
  for (int kc=0;kc<4;kc++)
    qf[kc] = *(const bf16x8*)&QKV[(size_t)(q0 + r)*QKVN + h*HDIM + kc*32 + kq*8];

  f32x4 oacc[8];
  #pragma unroll
  for (int d=0;d<8;d++) oacc[d] = {0.f,0.f,0.f,0.f};
  float mrow[4] = {-3e38f,-3e38f,-3e38f,-3e38f};
  float lsum[4] = {0.f,0.f,0.f,0.f};

  const unsigned short* Kbase = QKV + KOFS + kvh*HDIM;
  const unsigned short* Vbase = Vt + (size_t)kvh*HDIM*S_LEN;

  const int ntiles = qt + 1;
  for (int t=0;t<ntiles;t++){
    const int kv0 = t*64;
    __syncthreads();
    #pragma unroll
    for (int i=0;i<4;i++){
      int ci = (wv*4+i)*64 + lane;
      int kv = ci >> 4, ch = ci & 15;
      __builtin_amdgcn_global_load_lds(
        (const AS1 void*)(Kbase + (size_t)(kv0+kv)*QKVN + ((ch ^ (kv&7))*8)),
        (AS3 void*)((char*)Ks + (wv*4+i)*1024), 16, 0, 0);
    }
    #pragma unroll
    for (int i=0;i<4;i++){
      int ci = (wv*4+i)*64 + lane;
      int d = ci >> 3, ch = ci & 7;
      __builtin_amdgcn_global_load_lds(
        (const AS1 void*)(Vbase + (size_t)d*S_LEN + kv0 + ((ch ^ (d&7))*8)),
        (AS3 void*)((char*)Vs + (wv*4+i)*1024), 16, 0, 0);
    }
    __syncthreads();

    f32x4 s4[4];
    #pragma unroll
    for (int f=0;f<4;f++) s4[f] = {0.f,0.f,0.f,0.f};
    #pragma unroll
    for (int f=0;f<4;f++)
      #pragma unroll
      for (int kc=0;kc<4;kc++){
        bf16x8 kf = *(const bf16x8*)&Ks[(f*16+r)*128 + (((kc*4+kq) ^ (r&7))*8)];
        s4[f] = __builtin_amdgcn_mfma_f32_16x16x32_bf16(qf[kc], kf, s4[f], 0, 0, 0);
      }

    float sv[4][4]; float mx4[4];
    #pragma unroll
    for (int j=0;j<4;j++){
      int qg = q0 + kq*4 + j;
      #pragma unroll
      for (int f=0;f<4;f++)
        sv[j][f] = (kv0 + f*16 + r <= qg) ? s4[f][j]*scale : -3e38f;
      float mx = fmaxf(fmaxf(sv[j][0], sv[j][1]), fmaxf(sv[j][2], sv[j][3]));
      #pragma unroll
      for (int d=1; d<16; d<<=1) mx = fmaxf(mx, __shfl_xor(mx, d));
      mx4[j] = mx;
    }
    float need = fmaxf(fmaxf(mx4[0]-mrow[0], mx4[1]-mrow[1]),
                       fmaxf(mx4[2]-mrow[2], mx4[3]-mrow[3]));
    const bool defer = __all(need <= 8.0f);
    #pragma unroll
    for (int j=0;j<4;j++){
      float mnew = defer ? mrow[j] : fmaxf(mrow[j], mx4[j]);
      float alpha = defer ? 1.0f : exp2f((mrow[j]-mnew)*L2E);
      mrow[j] = mnew;
      float p0 = exp2f((sv[j][0]-mnew)*L2E);
      float p1 = exp2f((sv[j][1]-mnew)*L2E);
      float p2 = exp2f((sv[j][2]-mnew)*L2E);
      float p3 = exp2f((sv[j][3]-mnew)*L2E);
      float rs = (p0+p1)+(p2+p3);
      #pragma unroll
      for (int d=1; d<16; d<<=1) rs += __shfl_xor(rs, d);
      lsum[j] = lsum[j]*alpha + rs;
      if (!defer){
        #pragma unroll
        for (int df=0;df<8;df++) oacc[df][j] *= alpha;
      }
      bf16x4 pk; pk[0]=(short)f2bf(p0); pk[1]=(short)f2bf(p1); pk[2]=(short)f2bf(p2); pk[3]=(short)f2bf(p3);
      *(bf16x4*)&Pl[wv][kq*4+j][r*4] = pk;
    }

    bf16x8 pa0 = *(const bf16x8*)&Pl[wv][r][kq*8];
    bf16x8 pa1 = *(const bf16x8*)&Pl[wv][r][32 + kq*8];
    #pragma unroll
    for (int df=0;df<8;df++){
      int d = df*16 + r;
      bf16x8 v0 = *(const bf16x8*)&Vs[d*64 + ((kq ^ (r&7))*8)];
      bf16x8 v1 = *(const bf16x8*)&Vs[d*64 + (((4+kq) ^ (r&7))*8)];
      oacc[df] = __builtin_amdgcn_mfma_f32_16x16x32_bf16(pa0, v0, oacc[df], 0, 0, 0);
      oacc[df] = __builtin_amdgcn_mfma_f32_16x16x32_bf16(pa1, v1, oacc[df], 0, 0, 0);
    }
  }

  #pragma unroll
  for (int df=0;df<8;df++)
    #pragma unroll
    for (int j=0;j<4;j++){
      int qg = q0 + kq*4 + j;
      AO[(size_t)qg*HID + h*HDIM + df*16 + r] = f2bf(oacc[df][j] / lsum[j]);
    }
}

// ---------------- launch ----------------
extern "C" void kernel_launch(void* const* d_in, const int* in_sizes, int n_in,
                              void* d_out, int out_size, void* d_ws, size_t ws_size,
                              hipStream_t stream){
  (void)in_sizes; (void)n_in; (void)out_size; (void)ws_size;
  const float* hs = (const float*)d_in[0];
  const float* Wq = (const float*)d_in[1];
  const float* Wk = (const float*)d_in[2];
  const float* Wv = (const float*)d_in[3];
  const float* Wo = (const float*)d_in[4];
  float* out = (float*)d_out;
  char* ws = (char*)d_ws;
  size_t off = 0;
  auto alloc = [&](size_t bytes)->void*{ void* p = ws + off; off += (bytes + 255) & ~(size_t)255; return p; };

  unsigned short* Hb    = (unsigned short*)alloc((size_t)S_LEN*HID*2);
  unsigned short* Wqkvb = (unsigned short*)alloc((size_t)QKVN*HID*2);
  unsigned short* Wob   = (unsigned short*)alloc((size_t)HID*HID*2);
  unsigned short* QKVb  = (unsigned short*)alloc((size_t)S_LEN*QKVN*2);
  unsigned short* AOb   = (unsigned short*)alloc((size_t)S_LEN*HID*2);
  unsigned short* Vtb   = (unsigned short*)alloc((size_t)NKVH*HDIM*S_LEN*2);
  float* cosT = (float*)alloc((size_t)S_LEN*64*4);
  float* sinT = (float*)alloc((size_t)S_LEN*64*4);

  auto cvt = [&](const float* s, unsigned short* d, size_t n){
    int n4 = (int)(n/4);
    cvt_f32_bf16<<<(n4+255)/256, 256, 0, stream>>>(s, d, n4);
  };
  cvt(hs, Hb,  (size_t)S_LEN*HID);
  cvt(Wq, Wqkvb,                       (size_t)HID*HID);
  cvt(Wk, Wqkvb + (size_t)KOFS*HID,    (size_t)NKVH*HDIM*HID);
  cvt(Wv, Wqkvb + (size_t)VOFS*HID,    (size_t)NKVH*HDIM*HID);
  cvt(Wo, Wob, (size_t)HID*HID);
  rope_table<<<(S_LEN*64)/256, 256, 0, stream>>>(cosT, sinT);

  // fused QKV projection: BM=256, BN=192 -> grid 32x8 = 256 blocks (full machine)
  gemm_fr<256,192,0><<<dim3(QKVN/192, S_LEN/256), 512, 0, stream>>>(Hb, Wqkvb, QKVb, S_LEN, QKVN, HID);

  transpose_v<<<dim3(S_LEN/64, NKVH), 256, 0, stream>>>(QKVb, Vtb);

  int totQ = S_LEN*NHEADS*64;
  rope_apply<<<(totQ+255)/256, 256, 0, stream>>>(QKVb, cosT, sinT, NHEADS, QKVN, 0,    totQ);
  int totK = S_LEN*NKVH*64;
  rope_apply<<<(totK+255)/256, 256, 0, stream>>>(QKVb, cosT, sinT, NKVH,   QKVN, KOFS, totK);

  attn_fwd2<<<dim3(1024), 256, 0, stream>>>(QKVb, Vtb, AOb);

  // output projection: BM=128, BN=256 -> grid 16x16 = 256 blocks, fp32 epilogue
  gemm_fr<128,256,1><<<dim3(HID/256, S_LEN/128), 512, 0, stream>>>(AOb, Wob, out, S_LEN, HID, HID);
}

// Round 6
// 314.727 us; speedup vs baseline: 2.1369x; 1.0878x over previous
//
#include <hip/hip_runtime.h>

typedef __attribute__((ext_vector_type(8))) short bf16x8;
typedef __attribute__((ext_vector_type(4))) short bf16x4;
typedef __attribute__((ext_vector_type(4))) float f32x4;
typedef __attribute__((ext_vector_type(16))) float f32x16;

#define S_LEN  2048
#define HID    4096
#define NHEADS 32
#define NKVH   8
#define HDIM   128
#define QKVN   (HID + 2*NKVH*HDIM)   // 6144
#define KOFS   HID
#define VOFS   (HID + NKVH*HDIM)

#define AS1 __attribute__((address_space(1)))
#define AS3 __attribute__((address_space(3)))

__device__ __forceinline__ unsigned short f2bf(float f){
  unsigned int x = __float_as_uint(f);
  x += 0x7fffu + ((x >> 16) & 1u);
  return (unsigned short)(x >> 16);
}
__device__ __forceinline__ float bf2f(unsigned short h){
  return __uint_as_float(((unsigned int)h) << 16);
}

// ---------------- fp32 -> bf16 conversion ----------------
__global__ void cvt_f32_bf16(const float* __restrict__ src, unsigned short* __restrict__ dst, int n4){
  int i = blockIdx.x * blockDim.x + threadIdx.x;
  if (i < n4){
    float4 v = *(const float4*)(src + (size_t)i*4);
    ushort4 o;
    o.x = f2bf(v.x); o.y = f2bf(v.y); o.z = f2bf(v.z); o.w = f2bf(v.w);
    *(ushort4*)(dst + (size_t)i*4) = o;
  }
}

// ---------------- RoPE ----------------
__global__ void rope_table(float* __restrict__ cosT, float* __restrict__ sinT){
  int idx = blockIdx.x * blockDim.x + threadIdx.x;
  int s = idx >> 6, i = idx & 63;
  float inv = expf(-(float)i * (13.122363377404329f / 64.0f));
  float a = (float)s * inv;
  cosT[idx] = cosf(a);
  sinT[idx] = sinf(a);
}

__global__ void rope_apply(unsigned short* __restrict__ X, const float* __restrict__ cosT,
                           const float* __restrict__ sinT, int nh, int rowstr, int colofs, int total){
  int idx = blockIdx.x * blockDim.x + threadIdx.x;
  if (idx >= total) return;
  int i = idx & 63;
  int h = (idx >> 6) % nh;
  int s = idx / (64*nh);
  size_t base = (size_t)s*rowstr + colofs + h*HDIM + i;
  float x0 = bf2f(X[base]), x1 = bf2f(X[base+64]);
  float c = cosT[(s<<6)|i], sn = sinT[(s<<6)|i];
  X[base]    = f2bf(x0*c - x1*sn);
  X[base+64] = f2bf(x1*c + x0*sn);
}

// ---------------- V transpose: Vt[kvh][d][s] (plain) ----------------
__global__ __launch_bounds__(256) void transpose_v(const unsigned short* __restrict__ QKV,
                                                   unsigned short* __restrict__ Vt){
  __shared__ unsigned short T[64][130];
  const int qt = blockIdx.x, kvh = blockIdx.y;
  const int tid = threadIdx.x;
  #pragma unroll
  for (int i=0;i<4;i++){
    int c = tid + i*256;
    int sl = c >> 4;
    int d0 = (c & 15) * 8;
    bf16x8 v = *(const bf16x8*)&QKV[(size_t)(qt*64+sl)*QKVN + VOFS + kvh*HDIM + d0];
    #pragma unroll
    for (int j=0;j<8;j++) T[sl][d0+j] = (unsigned short)v[j];
  }
  __syncthreads();
  #pragma unroll
  for (int i=0;i<4;i++){
    int c = tid + i*256;
    int d = c >> 3;
    int p0 = (c & 7) * 8;
    bf16x8 o;
    #pragma unroll
    for (int j=0;j<8;j++) o[j] = (short)T[p0+j][d];
    *(bf16x8*)&Vt[((size_t)kvh*HDIM + d)*S_LEN + qt*64 + p0] = o;
  }
}

// ---- free-run bf16 GEMM: C[M,N] = A[M,K] @ W[N,K]^T (unchanged from r4) ----
template<int BM, int BN, int OUTF32>
__global__ __launch_bounds__(512, 2) void gemm_fr(const unsigned short* __restrict__ A,
                                                  const unsigned short* __restrict__ W,
                                                  void* __restrict__ C, int M, int N, int K){
  constexpr int MF = BM/32;
  constexpr int NF = BN/64;
  constexpr int LA = BM/64;
  constexpr int LB = BN/64;
  constexpr int ABYTES = BM*128;
  constexpr int BBYTES = BN*128;
  __shared__ char lds_raw[2*ABYTES + 2*BBYTES];

  const int tid = threadIdx.x;
  const int lane = tid & 63, wv = tid >> 6;
  const int wm = wv >> 2, wn = wv & 3;
  const int r = lane & 15, kq = lane >> 4;
  const int tn = blockIdx.x, tm = blockIdx.y;
  const unsigned short* Ab = A + (size_t)tm*BM*K;
  const unsigned short* Wb = W + (size_t)tn*BN*K;

  f32x4 acc[MF][NF];
  #pragma unroll
  for (int m=0;m<MF;m++)
    #pragma unroll
    for (int n=0;n<NF;n++) acc[m][n] = {0.f,0.f,0.f,0.f};

  auto stage = [&](int buf, int kt){
    #pragma unroll
    for (int l=0;l<LA;l++){
      int c = l*512 + tid;
      int row = c >> 3, ch = c & 7;
      __builtin_amdgcn_global_load_lds(
        (const AS1 void*)(Ab + (size_t)row*K + kt + ((ch ^ ((row>>1)&2))*8)),
        (AS3 void*)(lds_raw + buf*ABYTES + (l*512 + wv*64)*16), 16, 0, 0);
    }
    #pragma unroll
    for (int l=0;l<LB;l++){
      int c = l*512 + tid;
      int row = c >> 3, ch = c & 7;
      __builtin_amdgcn_global_load_lds(
        (const AS1 void*)(Wb + (size_t)row*K + kt + ((ch ^ ((row>>1)&2))*8)),
        (AS3 void*)(lds_raw + 2*ABYTES + buf*BBYTES + (l*512 + wv*64)*16), 16, 0, 0);
    }
  };
  auto rdA = [&](int buf, int m, int kh)->bf16x8 {
    int row = wm*(BM/2) + m*16 + r;
    int ch = (kh*4 + kq) ^ ((r>>1)&2);
    return *(const bf16x8*)(lds_raw + buf*ABYTES + row*128 + ch*16);
  };
  auto rdB = [&](int buf, int n, int kh)->bf16x8 {
    int row = wn*(BN/4) + n*16 + r;
    int ch = (kh*4 + kq) ^ ((r>>1)&2);
    return *(const bf16x8*)(lds_raw + 2*ABYTES + buf*BBYTES + row*128 + ch*16);
  };

  const int nt = K/64;
  stage(0, 0);
  for (int t=0; t<nt; ++t){
    asm volatile("s_waitcnt vmcnt(0)" ::: "memory");
    __builtin_amdgcn_s_barrier();
    if (t+1 < nt) stage((t+1)&1, (t+1)*64);
    const int buf = t & 1;
    #pragma unroll
    for (int kh=0; kh<2; ++kh){
      bf16x8 av[MF], bv[NF];
      #pragma unroll
      for (int m=0;m<MF;m++) av[m] = rdA(buf, m, kh);
      #pragma unroll
      for (int n=0;n<NF;n++) bv[n] = rdB(buf, n, kh);
      #pragma unroll
      for (int m=0;m<MF;m++)
        #pragma unroll
        for (int n=0;n<NF;n++)
          acc[m][n] = __builtin_amdgcn_mfma_f32_16x16x32_bf16(av[m], bv[n], acc[m][n], 0, 0, 0);
    }
  }

  #pragma unroll
  for (int m=0;m<MF;m++)
    #pragma unroll
    for (int n=0;n<NF;n++)
      #pragma unroll
      for (int j=0;j<4;j++){
        int gr = tm*BM + wm*(BM/2) + m*16 + kq*4 + j;
        int gc = tn*BN + wn*(BN/4) + n*16 + r;
        if (OUTF32) ((float*)C)[(size_t)gr*N + gc] = acc[m][n][j];
        else ((unsigned short*)C)[(size_t)gr*N + gc] = f2bf(acc[m][n][j]);
      }
}

// ---------------- attention v3b: swapped-QK^T 32x32 MFMA, in-register softmax ----
// 4 warps x 32 q rows = 128 q/block; KVBLK=64; grid 512 blocks (qt descending).
// QK^T swapped (A=K,B=Q): D[kv][q], q = lane&31, kv reg-dim = (i&3)+8*(i>>2)+4*(lane>>5).
// Fixed-reference softmax: P = exp2(min(S*CS - C0, 60)); exact after final division.
// PV A-frags assembled in-register via cvt_pk + __shfl_xor(.,32) (direction-free).
__global__ __launch_bounds__(256, 2) void attn_fwd3(const unsigned short* __restrict__ QKV,
                                                    const unsigned short* __restrict__ Vt,
                                                    unsigned short* __restrict__ AO){
  __shared__ unsigned short Ks[2][64*128];
  __shared__ unsigned short Vs[2][128*64];
  __shared__ float Ls[4][32];
  const int tid = threadIdx.x;
  const int lane = tid & 63, wv = tid >> 6;
  const int bid = blockIdx.x;
  const int h = bid & 31;
  const int qt = (S_LEN/128 - 1) - (bid >> 5);
  const int kvh = h >> 2;
  const int qb = qt * 128;
  const int q0w = qb + wv * 32;
  const int l31 = lane & 31, g = lane >> 5;
  const int qg = q0w + l31;

  const float CS = 0.12751743f;   // (1/sqrt(128)) * log2(e)
  const float C0 = 17.312340f;    // 12 * log2(e)  (fixed softmax reference)

  bf16x8 qf[8];
  #pragma unroll
  for (int st=0; st<8; ++st)
    qf[st] = *(const bf16x8*)&QKV[(size_t)qg*QKVN + h*HDIM + st*16 + g*8];

  f32x16 oacc[4];
  #pragma unroll
  for (int db=0; db<4; ++db)
    #pragma unroll
    for (int i=0;i<16;i++) oacc[db][i] = 0.f;
  float lsum = 0.f;

  const unsigned short* Kbase = QKV + KOFS + kvh*HDIM;
  const unsigned short* Vbase = Vt + (size_t)kvh*HDIM*S_LEN;

  auto stage = [&](int buf, int kv0){
    #pragma unroll
    for (int l=0; l<4; ++l){               // K: 64 rows x 256B (16 chunks), src-chunk = pos ^ (row&15)
      int c = l*256 + tid;
      int row = c >> 4, ch = c & 15;
      __builtin_amdgcn_global_load_lds(
        (const AS1 void*)(Kbase + (size_t)(kv0+row)*QKVN + ((ch ^ (row&15))*8)),
        (AS3 void*)((char*)&Ks[buf][0] + (l*256 + wv*64)*16), 16, 0, 0);
    }
    #pragma unroll
    for (int l=0; l<4; ++l){               // V: 128 rows x 128B (8 chunks), src-chunk = pos ^ (row&7)
      int c = l*256 + tid;
      int row = c >> 3, ch = c & 7;
      __builtin_amdgcn_global_load_lds(
        (const AS1 void*)(Vbase + (size_t)row*S_LEN + kv0 + ((ch ^ (row&7))*8)),
        (AS3 void*)((char*)&Vs[buf][0] + (l*256 + wv*64)*16), 16, 0, 0);
    }
  };

  const int nt = 2*qt + 2;
  stage(0, 0);
  for (int t=0; t<nt; ++t){
    __syncthreads();                       // drains vmcnt(0)+lgkmcnt(0) + full fence + barrier
    if (t+1 < nt) stage((t+1)&1, (t+1)*64);
    const int kv0 = t*64;
    if (kv0 > q0w + 31) continue;          // fully masked for this warp
    const unsigned short* K_ = &Ks[t&1][0];
    const unsigned short* V_ = &Vs[t&1][0];

    // QK^T swapped: A = K (rows=kv), B = Q (cols=q); k-slice d = 16*st + 8g + j
    f32x16 a0, a1;
    #pragma unroll
    for (int i=0;i<16;i++){ a0[i]=0.f; a1[i]=0.f; }
    #pragma unroll
    for (int st=0; st<8; ++st){
      int ch = (2*st + g) ^ (l31 & 15);
      bf16x8 k0 = *(const bf16x8*)&K_[ l31*128      + ch*8 ];
      int ch1 = (2*st + g) ^ ((32+l31) & 15);
      bf16x8 k1 = *(const bf16x8*)&K_[ (32+l31)*128 + ch1*8 ];
      a0 = __builtin_amdgcn_mfma_f32_32x32x16_bf16(k0, qf[st], a0, 0,0,0);
      a1 = __builtin_amdgcn_mfma_f32_32x32x16_bf16(k1, qf[st], a1, 0,0,0);
    }

    // softmax numerator (fixed reference; mask only diagonal-overlap tiles; clamped)
    float p0[16], p1[16];
    const bool dm = (kv0 + 63 > q0w);
    const int lim = qg - kv0 - 4*g;        // keep iff co <= lim (a0); co+32 <= lim (a1)
    #pragma unroll
    for (int i=0;i<16;i++){
      const int co = (i&3) + 8*(i>>2);
      float e0 = fmaf(a0[i], CS, -C0);
      float e1 = fmaf(a1[i], CS, -C0);
      if (dm){
        if (co      > lim) e0 = -200.f;
        if (co + 32 > lim) e1 = -200.f;
      }
      p0[i] = exp2f(fminf(e0, 60.f));
      p1[i] = exp2f(fminf(e1, 60.f));
    }
    {
      float u0 = (p0[0]+p0[1])+(p0[2]+p0[3]);
      float u1 = (p0[4]+p0[5])+(p0[6]+p0[7]);
      float u2 = (p0[8]+p0[9])+(p0[10]+p0[11]);
      float u3 = (p0[12]+p0[13])+(p0[14]+p0[15]);
      float v0 = (p1[0]+p1[1])+(p1[2]+p1[3]);
      float v1 = (p1[4]+p1[5])+(p1[6]+p1[7]);
      float v2 = (p1[8]+p1[9])+(p1[10]+p1[11]);
      float v3 = (p1[12]+p1[13])+(p1[14]+p1[15]);
      lsum += ((u0+u1)+(u2+u3)) + ((v0+v1)+(v2+v3));
    }

    // PV A-frags: lane (l31,g) needs P[q=l31][kv = u*16 + 8g + 0..7] as 4 u32 words.
    // own regs: w0,w1 = kv u16+4g+{0..3}; w2,w3 = kv u16+8+4g+{0..3}.
    // g=0 wants {w0,w1, other.w0, other.w1}; g=1 wants {other.w2, other.w3, w2,w3}.
    bf16x8 pa[4];
    #pragma unroll
    for (int u=0; u<4; ++u){
      const float* P = (u<2) ? p0 : p1;
      const int i0 = 8*(u&1);
      unsigned int w0,w1,w2,w3;
      asm("v_cvt_pk_bf16_f32 %0, %1, %2" : "=v"(w0) : "v"(P[i0+0]), "v"(P[i0+1]));
      asm("v_cvt_pk_bf16_f32 %0, %1, %2" : "=v"(w1) : "v"(P[i0+2]), "v"(P[i0+3]));
      asm("v_cvt_pk_bf16_f32 %0, %1, %2" : "=v"(w2) : "v"(P[i0+4]), "v"(P[i0+5]));
      asm("v_cvt_pk_bf16_f32 %0, %1, %2" : "=v"(w3) : "v"(P[i0+6]), "v"(P[i0+7]));
      unsigned int r0 = __shfl_xor(g ? w0 : w2, 32);  // g=0 rx other.w0 ; g=1 rx other.w2
      unsigned int r1 = __shfl_xor(g ? w1 : w3, 32);  // g=0 rx other.w1 ; g=1 rx other.w3
      union { unsigned int u4[4]; bf16x8 v; } pk;
      pk.u4[0] = g ? r0 : w0;
      pk.u4[1] = g ? r1 : w1;
      pk.u4[2] = g ? w2 : r0;
      pk.u4[3] = g ? w3 : r1;
      pa[u] = pk.v;
    }

    // PV: A = P[32q x 16kv], B = V[16kv x 32d] from transposed Vs
    #pragma unroll
    for (int u=0; u<4; ++u)
      #pragma unroll
      for (int db=0; db<4; ++db){
        int row = db*32 + l31;
        int ch = (2*u + g) ^ (row & 7);
        bf16x8 vb = *(const bf16x8*)&V_[row*64 + ch*8];
        oacc[db] = __builtin_amdgcn_mfma_f32_32x32x16_bf16(pa[u], vb, oacc[db], 0,0,0);
      }
  }

  // epilogue: combine lane-halves of lsum (direction-free), redistribute via LDS
  float ls = lsum + __shfl_xor(lsum, 32);
  float inv = 1.0f / fmaxf(ls, 1e-30f);
  Ls[wv][l31] = inv;
  #pragma unroll
  for (int ib=0; ib<4; ++ib){
    float4 iv = *(const float4*)&Ls[wv][8*ib + 4*g];
    float ivv[4] = {iv.x, iv.y, iv.z, iv.w};
    #pragma unroll
    for (int c3=0; c3<4; ++c3){
      int row = 8*ib + 4*g + c3;
      #pragma unroll
      for (int db=0; db<4; ++db){
        AO[(size_t)(qb + wv*32 + row)*HID + h*HDIM + db*32 + l31] =
          f2bf(oacc[db][4*ib+c3] * ivv[c3]);
      }
    }
  }
}

// ---------------- launch ----------------
extern "C" void kernel_launch(void* const* d_in, const int* in_sizes, int n_in,
                              void* d_out, int out_size, void* d_ws, size_t ws_size,
                              hipStream_t stream){
  (void)in_sizes; (void)n_in; (void)out_size; (void)ws_size;
  const float* hs = (const float*)d_in[0];
  const float* Wq = (const float*)d_in[1];
  const float* Wk = (const float*)d_in[2];
  const float* Wv = (const float*)d_in[3];
  const float* Wo = (const float*)d_in[4];
  float* out = (float*)d_out;
  char* ws = (char*)d_ws;
  size_t off = 0;
  auto alloc = [&](size_t bytes)->void*{ void* p = ws + off; off += (bytes + 255) & ~(size_t)255; return p; };

  unsigned short* Hb    = (unsigned short*)alloc((size_t)S_LEN*HID*2);
  unsigned short* Wqkvb = (unsigned short*)alloc((size_t)QKVN*HID*2);
  unsigned short* Wob   = (unsigned short*)alloc((size_t)HID*HID*2);
  unsigned short* QKVb  = (unsigned short*)alloc((size_t)S_LEN*QKVN*2);
  unsigned short* AOb   = (unsigned short*)alloc((size_t)S_LEN*HID*2);
  unsigned short* Vtb   = (unsigned short*)alloc((size_t)NKVH*HDIM*S_LEN*2);
  float* cosT = (float*)alloc((size_t)S_LEN*64*4);
  float* sinT = (float*)alloc((size_t)S_LEN*64*4);

  auto cvt = [&](const float* s, unsigned short* d, size_t n){
    int n4 = (int)(n/4);
    cvt_f32_bf16<<<(n4+255)/256, 256, 0, stream>>>(s, d, n4);
  };
  cvt(hs, Hb,  (size_t)S_LEN*HID);
  cvt(Wq, Wqkvb,                       (size_t)HID*HID);
  cvt(Wk, Wqkvb + (size_t)KOFS*HID,    (size_t)NKVH*HDIM*HID);
  cvt(Wv, Wqkvb + (size_t)VOFS*HID,    (size_t)NKVH*HDIM*HID);
  cvt(Wo, Wob, (size_t)HID*HID);
  rope_table<<<(S_LEN*64)/256, 256, 0, stream>>>(cosT, sinT);

  // fused QKV projection: BM=256, BN=192 -> 256 blocks
  gemm_fr<256,192,0><<<dim3(QKVN/192, S_LEN/256), 512, 0, stream>>>(Hb, Wqkvb, QKVb, S_LEN, QKVN, HID);

  transpose_v<<<dim3(S_LEN/64, NKVH), 256, 0, stream>>>(QKVb, Vtb);

  int totQ = S_LEN*NHEADS*64;
  rope_apply<<<(totQ+255)/256, 256, 0, stream>>>(QKVb, cosT, sinT, NHEADS, QKVN, 0,    totQ);
  int totK = S_LEN*NKVH*64;
  rope_apply<<<(totK+255)/256, 256, 0, stream>>>(QKVb, cosT, sinT, NKVH,   QKVN, KOFS, totK);

  // attention: 16 q-tiles of 128 (descending) x 32 heads = 512 blocks
  attn_fwd3<<<dim3(512), 256, 0, stream>>>(QKVb, Vtb, AOb);

  // output projection: BM=128, BN=256 -> 256 blocks, fp32 epilogue
  gemm_fr<128,256,1><<<dim3(HID/256, S_LEN/128), 512, 0, stream>>>(AOb, Wob, out, S_LEN, HID, HID);
}

// Round 7
// 299.470 us; speedup vs baseline: 2.2457x; 1.0509x over previous
//
#include <hip/hip_runtime.h>

typedef __attribute__((ext_vector_type(8))) short bf16x8;
typedef __attribute__((ext_vector_type(4))) short bf16x4;
typedef __attribute__((ext_vector_type(4))) float f32x4;
typedef __attribute__((ext_vector_type(16))) float f32x16;

#define S_LEN  2048
#define HID    4096
#define NHEADS 32
#define NKVH   8
#define HDIM   128
#define QKVN   (HID + 2*NKVH*HDIM)   // 6144
#define KOFS   HID
#define VOFS   (HID + NKVH*HDIM)

#define AS1 __attribute__((address_space(1)))
#define AS3 __attribute__((address_space(3)))

__device__ __forceinline__ unsigned short f2bf(float f){
  unsigned int x = __float_as_uint(f);
  x += 0x7fffu + ((x >> 16) & 1u);
  return (unsigned short)(x >> 16);
}
__device__ __forceinline__ float bf2f(unsigned short h){
  return __uint_as_float(((unsigned int)h) << 16);
}

// ---------------- fused fp32 -> bf16 conversion (all 5 tensors, one launch) ----
// float4-unit region map:
//  [0, 2097152)              hs  -> Hb
//  [2097152, 6291456)        Wq  -> Wqkvb + 0
//  [6291456, 7340032)        Wk  -> Wqkvb + 4194304 (f4 units)
//  [7340032, 8388608)        Wv  -> Wqkvb + 5242880
//  [8388608, 12582912)       Wo  -> Wob
__global__ void cvt_all(const float* __restrict__ hs, const float* __restrict__ wq,
                        const float* __restrict__ wk, const float* __restrict__ wv,
                        const float* __restrict__ wo,
                        unsigned short* __restrict__ Hb,
                        unsigned short* __restrict__ Wqkvb,
                        unsigned short* __restrict__ Wob){
  const int total = 12582912;
  for (int i = blockIdx.x * blockDim.x + threadIdx.x; i < total; i += gridDim.x * blockDim.x){
    const float* src; unsigned short* dst;
    if (i < 2097152)      { src = hs + (size_t)i*4;             dst = Hb    + (size_t)i*4; }
    else if (i < 6291456) { size_t l = i - 2097152;  src = wq + l*4; dst = Wqkvb + l*4; }
    else if (i < 7340032) { size_t l = i - 6291456;  src = wk + l*4; dst = Wqkvb + 16777216 + l*4; }
    else if (i < 8388608) { size_t l = i - 7340032;  src = wv + l*4; dst = Wqkvb + 20971520 + l*4; }
    else                  { size_t l = i - 8388608;  src = wo + l*4; dst = Wob   + l*4; }
    float4 v = *(const float4*)src;
    ushort4 o;
    o.x = f2bf(v.x); o.y = f2bf(v.y); o.z = f2bf(v.z); o.w = f2bf(v.w);
    *(ushort4*)dst = o;
  }
}

// ---------------- RoPE ----------------
__global__ void rope_table(float* __restrict__ cosT, float* __restrict__ sinT){
  int idx = blockIdx.x * blockDim.x + threadIdx.x;
  int s = idx >> 6, i = idx & 63;
  float inv = expf(-(float)i * (13.122363377404329f / 64.0f));
  float a = (float)s * inv;
  cosT[idx] = cosf(a);
  sinT[idx] = sinf(a);
}

__global__ void rope_apply(unsigned short* __restrict__ X, const float* __restrict__ cosT,
                           const float* __restrict__ sinT, int nh, int rowstr, int colofs, int total){
  int idx = blockIdx.x * blockDim.x + threadIdx.x;
  if (idx >= total) return;
  int i = idx & 63;
  int h = (idx >> 6) % nh;
  int s = idx / (64*nh);
  size_t base = (size_t)s*rowstr + colofs + h*HDIM + i;
  float x0 = bf2f(X[base]), x1 = bf2f(X[base+64]);
  float c = cosT[(s<<6)|i], sn = sinT[(s<<6)|i];
  X[base]    = f2bf(x0*c - x1*sn);
  X[base+64] = f2bf(x1*c + x0*sn);
}

// ---------------- V transpose: Vt[kvh][d][s] (plain) ----------------
__global__ __launch_bounds__(256) void transpose_v(const unsigned short* __restrict__ QKV,
                                                   unsigned short* __restrict__ Vt){
  __shared__ unsigned short T[64][130];
  const int qt = blockIdx.x, kvh = blockIdx.y;
  const int tid = threadIdx.x;
  #pragma unroll
  for (int i=0;i<4;i++){
    int c = tid + i*256;
    int sl = c >> 4;
    int d0 = (c & 15) * 8;
    bf16x8 v = *(const bf16x8*)&QKV[(size_t)(qt*64+sl)*QKVN + VOFS + kvh*HDIM + d0];
    #pragma unroll
    for (int j=0;j<8;j++) T[sl][d0+j] = (unsigned short)v[j];
  }
  __syncthreads();
  #pragma unroll
  for (int i=0;i<4;i++){
    int c = tid + i*256;
    int d = c >> 3;
    int p0 = (c & 7) * 8;
    bf16x8 o;
    #pragma unroll
    for (int j=0;j<8;j++) o[j] = (short)T[p0+j][d];
    *(bf16x8*)&Vt[((size_t)kvh*HDIM + d)*S_LEN + qt*64 + p0] = o;
  }
}

// ---- free-run bf16 GEMM: C[M,N] = A[M,K] @ W[N,K]^T ------------------------
// BK=64 (128B rows). Full-spread XOR swizzle: chunk bits 1-2 ^= row bits 1-2,
// applied to BOTH the pre-swizzled global_load_lds source and the ds_read
// (rule 21 involution). Fragment ds_read_b128 then hits all 32 banks (8
// lanes/chunk = wave64 floor). Double-buffered; one vmcnt(0)+barrier per
// K-tile; interior free-runs (compiler schedules LDS reads vs MFMA).
template<int BM, int BN, int OUTF32>
__global__ __launch_bounds__(512, 2) void gemm_fr(const unsigned short* __restrict__ A,
                                                  const unsigned short* __restrict__ W,
                                                  void* __restrict__ C, int M, int N, int K){
  constexpr int MF = BM/32;
  constexpr int NF = BN/64;
  constexpr int LA = BM/64;
  constexpr int LB = BN/64;
  constexpr int ABYTES = BM*128;
  constexpr int BBYTES = BN*128;
  __shared__ char lds_raw[2*ABYTES + 2*BBYTES];

  const int tid = threadIdx.x;
  const int lane = tid & 63, wv = tid >> 6;
  const int wm = wv >> 2, wn = wv & 3;
  const int r = lane & 15, kq = lane >> 4;
  const int tn = blockIdx.x, tm = blockIdx.y;
  const unsigned short* Ab = A + (size_t)tm*BM*K;
  const unsigned short* Wb = W + (size_t)tn*BN*K;

  f32x4 acc[MF][NF];
  #pragma unroll
  for (int m=0;m<MF;m++)
    #pragma unroll
    for (int n=0;n<NF;n++) acc[m][n] = {0.f,0.f,0.f,0.f};

  auto swz = [](int row)->int { return ((row>>1)&3)<<1; };   // chunk bits 1-2 from row bits 1-2

  auto stage = [&](int buf, int kt){
    #pragma unroll
    for (int l=0;l<LA;l++){
      int c = l*512 + tid;
      int row = c >> 3, ch = c & 7;
      __builtin_amdgcn_global_load_lds(
        (const AS1 void*)(Ab + (size_t)row*K + kt + ((ch ^ swz(row))*8)),
        (AS3 void*)(lds_raw + buf*ABYTES + (l*512 + wv*64)*16), 16, 0, 0);
    }
    #pragma unroll
    for (int l=0;l<LB;l++){
      int c = l*512 + tid;
      int row = c >> 3, ch = c & 7;
      __builtin_amdgcn_global_load_lds(
        (const AS1 void*)(Wb + (size_t)row*K + kt + ((ch ^ swz(row))*8)),
        (AS3 void*)(lds_raw + 2*ABYTES + buf*BBYTES + (l*512 + wv*64)*16), 16, 0, 0);
    }
  };
  auto rdA = [&](int buf, int m, int kh)->bf16x8 {
    int row = wm*(BM/2) + m*16 + r;
    int ch = (kh*4 + kq) ^ swz(row);
    return *(const bf16x8*)(lds_raw + buf*ABYTES + row*128 + ch*16);
  };
  auto rdB = [&](int buf, int n, int kh)->bf16x8 {
    int row = wn*(BN/4) + n*16 + r;
    int ch = (kh*4 + kq) ^ swz(row);
    return *(const bf16x8*)(lds_raw + 2*ABYTES + buf*BBYTES + row*128 + ch*16);
  };

  const int nt = K/64;
  stage(0, 0);
  for (int t=0; t<nt; ++t){
    asm volatile("s_waitcnt vmcnt(0)" ::: "memory");
    __builtin_amdgcn_s_barrier();
    if (t+1 < nt) stage((t+1)&1, (t+1)*64);
    const int buf = t & 1;
    #pragma unroll
    for (int kh=0; kh<2; ++kh){
      bf16x8 av[MF], bv[NF];
      #pragma unroll
      for (int m=0;m<MF;m++) av[m] = rdA(buf, m, kh);
      #pragma unroll
      for (int n=0;n<NF;n++) bv[n] = rdB(buf, n, kh);
      #pragma unroll
      for (int m=0;m<MF;m++)
        #pragma unroll
        for (int n=0;n<NF;n++)
          acc[m][n] = __builtin_amdgcn_mfma_f32_16x16x32_bf16(av[m], bv[n], acc[m][n], 0, 0, 0);
    }
  }

  #pragma unroll
  for (int m=0;m<MF;m++)
    #pragma unroll
    for (int n=0;n<NF;n++)
      #pragma unroll
      for (int j=0;j<4;j++){
        int gr = tm*BM + wm*(BM/2) + m*16 + kq*4 + j;
        int gc = tn*BN + wn*(BN/4) + n*16 + r;
        if (OUTF32) ((float*)C)[(size_t)gr*N + gc] = acc[m][n][j];
        else ((unsigned short*)C)[(size_t)gr*N + gc] = f2bf(acc[m][n][j]);
      }
}

// ---------------- attention v3b: swapped-QK^T 32x32 MFMA, in-register softmax ----
// (unchanged from r6 — passed, off the critical top-5)
__global__ __launch_bounds__(256, 2) void attn_fwd3(const unsigned short* __restrict__ QKV,
                                                    const unsigned short* __restrict__ Vt,
                                                    unsigned short* __restrict__ AO){
  __shared__ unsigned short Ks[2][64*128];
  __shared__ unsigned short Vs[2][128*64];
  __shared__ float Ls[4][32];
  const int tid = threadIdx.x;
  const int lane = tid & 63, wv = tid >> 6;
  const int bid = blockIdx.x;
  const int h = bid & 31;
  const int qt = (S_LEN/128 - 1) - (bid >> 5);
  const int kvh = h >> 2;
  const int qb = qt * 128;
  const int q0w = qb + wv * 32;
  const int l31 = lane & 31, g = lane >> 5;
  const int qg = q0w + l31;

  const float CS = 0.12751743f;   // (1/sqrt(128)) * log2(e)
  const float C0 = 17.312340f;    // 12 * log2(e)

  bf16x8 qf[8];
  #pragma unroll
  for (int st=0; st<8; ++st)
    qf[st] = *(const bf16x8*)&QKV[(size_t)qg*QKVN + h*HDIM + st*16 + g*8];

  f32x16 oacc[4];
  #pragma unroll
  for (int db=0; db<4; ++db)
    #pragma unroll
    for (int i=0;i<16;i++) oacc[db][i] = 0.f;
  float lsum = 0.f;

  const unsigned short* Kbase = QKV + KOFS + kvh*HDIM;
  const unsigned short* Vbase = Vt + (size_t)kvh*HDIM*S_LEN;

  auto stage = [&](int buf, int kv0){
    #pragma unroll
    for (int l=0; l<4; ++l){
      int c = l*256 + tid;
      int row = c >> 4, ch = c & 15;
      __builtin_amdgcn_global_load_lds(
        (const AS1 void*)(Kbase + (size_t)(kv0+row)*QKVN + ((ch ^ (row&15))*8)),
        (AS3 void*)((char*)&Ks[buf][0] + (l*256 + wv*64)*16), 16, 0, 0);
    }
    #pragma unroll
    for (int l=0; l<4; ++l){
      int c = l*256 + tid;
      int row = c >> 3, ch = c & 7;
      __builtin_amdgcn_global_load_lds(
        (const AS1 void*)(Vbase + (size_t)row*S_LEN + kv0 + ((ch ^ (row&7))*8)),
        (AS3 void*)((char*)&Vs[buf][0] + (l*256 + wv*64)*16), 16, 0, 0);
    }
  };

  const int nt = 2*qt + 2;
  stage(0, 0);
  for (int t=0; t<nt; ++t){
    __syncthreads();
    if (t+1 < nt) stage((t+1)&1, (t+1)*64);
    const int kv0 = t*64;
    if (kv0 > q0w + 31) continue;
    const unsigned short* K_ = &Ks[t&1][0];
    const unsigned short* V_ = &Vs[t&1][0];

    f32x16 a0, a1;
    #pragma unroll
    for (int i=0;i<16;i++){ a0[i]=0.f; a1[i]=0.f; }
    #pragma unroll
    for (int st=0; st<8; ++st){
      int ch = (2*st + g) ^ (l31 & 15);
      bf16x8 k0 = *(const bf16x8*)&K_[ l31*128      + ch*8 ];
      int ch1 = (2*st + g) ^ ((32+l31) & 15);
      bf16x8 k1 = *(const bf16x8*)&K_[ (32+l31)*128 + ch1*8 ];
      a0 = __builtin_amdgcn_mfma_f32_32x32x16_bf16(k0, qf[st], a0, 0,0,0);
      a1 = __builtin_amdgcn_mfma_f32_32x32x16_bf16(k1, qf[st], a1, 0,0,0);
    }

    float p0[16], p1[16];
    const bool dm = (kv0 + 63 > q0w);
    const int lim = qg - kv0 - 4*g;
    #pragma unroll
    for (int i=0;i<16;i++){
      const int co = (i&3) + 8*(i>>2);
      float e0 = fmaf(a0[i], CS, -C0);
      float e1 = fmaf(a1[i], CS, -C0);
      if (dm){
        if (co      > lim) e0 = -200.f;
        if (co + 32 > lim) e1 = -200.f;
      }
      p0[i] = exp2f(fminf(e0, 60.f));
      p1[i] = exp2f(fminf(e1, 60.f));
    }
    {
      float u0 = (p0[0]+p0[1])+(p0[2]+p0[3]);
      float u1 = (p0[4]+p0[5])+(p0[6]+p0[7]);
      float u2 = (p0[8]+p0[9])+(p0[10]+p0[11]);
      float u3 = (p0[12]+p0[13])+(p0[14]+p0[15]);
      float v0 = (p1[0]+p1[1])+(p1[2]+p1[3]);
      float v1 = (p1[4]+p1[5])+(p1[6]+p1[7]);
      float v2 = (p1[8]+p1[9])+(p1[10]+p1[11]);
      float v3 = (p1[12]+p1[13])+(p1[14]+p1[15]);
      lsum += ((u0+u1)+(u2+u3)) + ((v0+v1)+(v2+v3));
    }

    bf16x8 pa[4];
    #pragma unroll
    for (int u=0; u<4; ++u){
      const float* P = (u<2) ? p0 : p1;
      const int i0 = 8*(u&1);
      unsigned int w0,w1,w2,w3;
      asm("v_cvt_pk_bf16_f32 %0, %1, %2" : "=v"(w0) : "v"(P[i0+0]), "v"(P[i0+1]));
      asm("v_cvt_pk_bf16_f32 %0, %1, %2" : "=v"(w1) : "v"(P[i0+2]), "v"(P[i0+3]));
      asm("v_cvt_pk_bf16_f32 %0, %1, %2" : "=v"(w2) : "v"(P[i0+4]), "v"(P[i0+5]));
      asm("v_cvt_pk_bf16_f32 %0, %1, %2" : "=v"(w3) : "v"(P[i0+6]), "v"(P[i0+7]));
      unsigned int r0 = __shfl_xor(g ? w0 : w2, 32);
      unsigned int r1 = __shfl_xor(g ? w1 : w3, 32);
      union { unsigned int u4[4]; bf16x8 v; } pk;
      pk.u4[0] = g ? r0 : w0;
      pk.u4[1] = g ? r1 : w1;
      pk.u4[2] = g ? w2 : r0;
      pk.u4[3] = g ? w3 : r1;
      pa[u] = pk.v;
    }

    #pragma unroll
    for (int u=0; u<4; ++u)
      #pragma unroll
      for (int db=0; db<4; ++db){
        int row = db*32 + l31;
        int ch = (2*u + g) ^ (row & 7);
        bf16x8 vb = *(const bf16x8*)&V_[row*64 + ch*8];
        oacc[db] = __builtin_amdgcn_mfma_f32_32x32x16_bf16(pa[u], vb, oacc[db], 0,0,0);
      }
  }

  float ls = lsum + __shfl_xor(lsum, 32);
  float inv = 1.0f / fmaxf(ls, 1e-30f);
  Ls[wv][l31] = inv;
  #pragma unroll
  for (int ib=0; ib<4; ++ib){
    float4 iv = *(const float4*)&Ls[wv][8*ib + 4*g];
    float ivv[4] = {iv.x, iv.y, iv.z, iv.w};
    #pragma unroll
    for (int c3=0; c3<4; ++c3){
      int row = 8*ib + 4*g + c3;
      #pragma unroll
      for (int db=0; db<4; ++db){
        AO[(size_t)(qb + wv*32 + row)*HID + h*HDIM + db*32 + l31] =
          f2bf(oacc[db][4*ib+c3] * ivv[c3]);
      }
    }
  }
}

// ---------------- launch ----------------
extern "C" void kernel_launch(void* const* d_in, const int* in_sizes, int n_in,
                              void* d_out, int out_size, void* d_ws, size_t ws_size,
                              hipStream_t stream){
  (void)in_sizes; (void)n_in; (void)out_size; (void)ws_size;
  const float* hs = (const float*)d_in[0];
  const float* Wq = (const float*)d_in[1];
  const float* Wk = (const float*)d_in[2];
  const float* Wv = (const float*)d_in[3];
  const float* Wo = (const float*)d_in[4];
  float* out = (float*)d_out;
  char* ws = (char*)d_ws;
  size_t off = 0;
  auto alloc = [&](size_t bytes)->void*{ void* p = ws + off; off += (bytes + 255) & ~(size_t)255; return p; };

  unsigned short* Hb    = (unsigned short*)alloc((size_t)S_LEN*HID*2);
  unsigned short* Wqkvb = (unsigned short*)alloc((size_t)QKVN*HID*2);
  unsigned short* Wob   = (unsigned short*)alloc((size_t)HID*HID*2);
  unsigned short* QKVb  = (unsigned short*)alloc((size_t)S_LEN*QKVN*2);
  unsigned short* AOb   = (unsigned short*)alloc((size_t)S_LEN*HID*2);
  unsigned short* Vtb   = (unsigned short*)alloc((size_t)NKVH*HDIM*S_LEN*2);
  float* cosT = (float*)alloc((size_t)S_LEN*64*4);
  float* sinT = (float*)alloc((size_t)S_LEN*64*4);

  // fused conversion of all inputs (one launch, grid-stride)
  cvt_all<<<2048, 256, 0, stream>>>(hs, Wq, Wk, Wv, Wo, Hb, Wqkvb, Wob);
  rope_table<<<(S_LEN*64)/256, 256, 0, stream>>>(cosT, sinT);

  // fused QKV projection: BM=256, BN=192 -> 256 blocks
  gemm_fr<256,192,0><<<dim3(QKVN/192, S_LEN/256), 512, 0, stream>>>(Hb, Wqkvb, QKVb, S_LEN, QKVN, HID);

  transpose_v<<<dim3(S_LEN/64, NKVH), 256, 0, stream>>>(QKVb, Vtb);

  int totQ = S_LEN*NHEADS*64;
  rope_apply<<<(totQ+255)/256, 256, 0, stream>>>(QKVb, cosT, sinT, NHEADS, QKVN, 0,    totQ);
  int totK = S_LEN*NKVH*64;
  rope_apply<<<(totK+255)/256, 256, 0, stream>>>(QKVb, cosT, sinT, NKVH,   QKVN, KOFS, totK);

  // attention: 16 q-tiles of 128 (descending) x 32 heads = 512 blocks
  attn_fwd3<<<dim3(512), 256, 0, stream>>>(QKVb, Vtb, AOb);

  // output projection: BM=128, BN=256 -> 256 blocks, fp32 epilogue
  gemm_fr<128,256,1><<<dim3(HID/256, S_LEN/128), 512, 0, stream>>>(AOb, Wob, out, S_LEN, HID, HID);
}

// Round 8
// 298.650 us; speedup vs baseline: 2.2519x; 1.0027x over previous
//
#include <hip/hip_runtime.h>

typedef __attribute__((ext_vector_type(8))) short bf16x8;
typedef __attribute__((ext_vector_type(4))) short bf16x4;
typedef __attribute__((ext_vector_type(4))) float f32x4;
typedef __attribute__((ext_vector_type(16))) float f32x16;

#define S_LEN  2048
#define HID    4096
#define NHEADS 32
#define NKVH   8
#define HDIM   128
#define QKVN   (HID + 2*NKVH*HDIM)   // 6144
#define KOFS   HID
#define VOFS   (HID + NKVH*HDIM)

#define AS1 __attribute__((address_space(1)))
#define AS3 __attribute__((address_space(3)))

__device__ __forceinline__ unsigned short f2bf(float f){
  unsigned int x = __float_as_uint(f);
  x += 0x7fffu + ((x >> 16) & 1u);
  return (unsigned short)(x >> 16);
}
__device__ __forceinline__ float bf2f(unsigned short h){
  return __uint_as_float(((unsigned int)h) << 16);
}

// ---------------- fused fp32 -> bf16 conversion (all 5 tensors, one launch) ----
__global__ void cvt_all(const float* __restrict__ hs, const float* __restrict__ wq,
                        const float* __restrict__ wk, const float* __restrict__ wv,
                        const float* __restrict__ wo,
                        unsigned short* __restrict__ Hb,
                        unsigned short* __restrict__ Wqkvb,
                        unsigned short* __restrict__ Wob){
  const int total = 12582912;
  for (int i = blockIdx.x * blockDim.x + threadIdx.x; i < total; i += gridDim.x * blockDim.x){
    const float* src; unsigned short* dst;
    if (i < 2097152)      { src = hs + (size_t)i*4;             dst = Hb    + (size_t)i*4; }
    else if (i < 6291456) { size_t l = i - 2097152;  src = wq + l*4; dst = Wqkvb + l*4; }
    else if (i < 7340032) { size_t l = i - 6291456;  src = wk + l*4; dst = Wqkvb + 16777216 + l*4; }
    else if (i < 8388608) { size_t l = i - 7340032;  src = wv + l*4; dst = Wqkvb + 20971520 + l*4; }
    else                  { size_t l = i - 8388608;  src = wo + l*4; dst = Wob   + l*4; }
    float4 v = *(const float4*)src;
    ushort4 o;
    o.x = f2bf(v.x); o.y = f2bf(v.y); o.z = f2bf(v.z); o.w = f2bf(v.w);
    *(ushort4*)dst = o;
  }
}

// ---------------- RoPE ----------------
__global__ void rope_table(float* __restrict__ cosT, float* __restrict__ sinT){
  int idx = blockIdx.x * blockDim.x + threadIdx.x;
  int s = idx >> 6, i = idx & 63;
  float inv = expf(-(float)i * (13.122363377404329f / 64.0f));
  float a = (float)s * inv;
  cosT[idx] = cosf(a);
  sinT[idx] = sinf(a);
}

// merged Q+K rope (one launch)
__global__ void rope_apply2(unsigned short* __restrict__ X, const float* __restrict__ cosT,
                            const float* __restrict__ sinT){
  const int totQ = S_LEN*NHEADS*64;
  const int total = totQ + S_LEN*NKVH*64;
  int idx = blockIdx.x * blockDim.x + threadIdx.x;
  if (idx >= total) return;
  int nh, colofs, local;
  if (idx < totQ){ nh = NHEADS; colofs = 0;    local = idx; }
  else           { nh = NKVH;   colofs = KOFS; local = idx - totQ; }
  int i = local & 63;
  int h = (local >> 6) % nh;
  int s = local / (64*nh);
  size_t base = (size_t)s*QKVN + colofs + h*HDIM + i;
  float x0 = bf2f(X[base]), x1 = bf2f(X[base+64]);
  float c = cosT[(s<<6)|i], sn = sinT[(s<<6)|i];
  X[base]    = f2bf(x0*c - x1*sn);
  X[base+64] = f2bf(x1*c + x0*sn);
}

// ---------------- V transpose: Vt[kvh][d][s] (unchanged) ----------------
__global__ __launch_bounds__(256) void transpose_v(const unsigned short* __restrict__ QKV,
                                                   unsigned short* __restrict__ Vt){
  __shared__ unsigned short T[64][130];
  const int qt = blockIdx.x, kvh = blockIdx.y;
  const int tid = threadIdx.x;
  #pragma unroll
  for (int i=0;i<4;i++){
    int c = tid + i*256;
    int sl = c >> 4;
    int d0 = (c & 15) * 8;
    bf16x8 v = *(const bf16x8*)&QKV[(size_t)(qt*64+sl)*QKVN + VOFS + kvh*HDIM + d0];
    #pragma unroll
    for (int j=0;j<8;j++) T[sl][d0+j] = (unsigned short)v[j];
  }
  __syncthreads();
  #pragma unroll
  for (int i=0;i<4;i++){
    int c = tid + i*256;
    int d = c >> 3;
    int p0 = (c & 7) * 8;
    bf16x8 o;
    #pragma unroll
    for (int j=0;j<8;j++) o[j] = (short)T[p0+j][d];
    *(bf16x8*)&Vt[((size_t)kvh*HDIM + d)*S_LEN + qt*64 + p0] = o;
  }
}

// ---- free-run bf16 GEMM v4: C[M,N] = A[M,K] @ W[N,K]^T ---------------------
// 4 waves (256 thr), BM=128 so grid hits 512 blocks -> 2 independent blocks/CU
// (separate barrier domains anti-phase the LDS and MFMA pipes; m97/m114).
// BK=64 (128B rows), full-spread XOR swizzle on both gload source and ds_read.
// Double-buffered; one vmcnt(0)+barrier per K-tile; interior free-runs.
template<int BM, int BN, int WM, int WN, int OUTF32>
__global__ __launch_bounds__(256, 2) void gemm_fr(const unsigned short* __restrict__ A,
                                                  const unsigned short* __restrict__ W,
                                                  void* __restrict__ C, int M, int N, int K){
  constexpr int MF = (BM/WM)/16;
  constexpr int NF = (BN/WN)/16;
  constexpr int LA = BM/32;            // A gload instrs per tile (256 thr x 16B = 4KB each)
  constexpr int LB = BN/32;
  constexpr int ABYTES = BM*128;
  constexpr int BBYTES = BN*128;
  __shared__ char lds_raw[2*ABYTES + 2*BBYTES];

  const int tid = threadIdx.x;
  const int lane = tid & 63, wv = tid >> 6;
  const int wm = wv / WN, wn = wv % WN;
  const int r = lane & 15, kq = lane >> 4;
  const int tn = blockIdx.x, tm = blockIdx.y;
  const unsigned short* Ab = A + (size_t)tm*BM*K;
  const unsigned short* Wb = W + (size_t)tn*BN*K;

  f32x4 acc[MF][NF];
  #pragma unroll
  for (int m=0;m<MF;m++)
    #pragma unroll
    for (int n=0;n<NF;n++) acc[m][n] = {0.f,0.f,0.f,0.f};

  auto swz = [](int row)->int { return ((row>>1)&3)<<1; };

  auto stage = [&](int buf, int kt){
    #pragma unroll
    for (int l=0;l<LA;l++){
      int c = l*256 + tid;
      int row = c >> 3, ch = c & 7;
      __builtin_amdgcn_global_load_lds(
        (const AS1 void*)(Ab + (size_t)row*K + kt + ((ch ^ swz(row))*8)),
        (AS3 void*)(lds_raw + buf*ABYTES + (l*256 + wv*64)*16), 16, 0, 0);
    }
    #pragma unroll
    for (int l=0;l<LB;l++){
      int c = l*256 + tid;
      int row = c >> 3, ch = c & 7;
      __builtin_amdgcn_global_load_lds(
        (const AS1 void*)(Wb + (size_t)row*K + kt + ((ch ^ swz(row))*8)),
        (AS3 void*)(lds_raw + 2*ABYTES + buf*BBYTES + (l*256 + wv*64)*16), 16, 0, 0);
    }
  };
  auto rdA = [&](int buf, int m, int kh)->bf16x8 {
    int row = wm*(BM/WM) + m*16 + r;
    int ch = (kh*4 + kq) ^ swz(row);
    return *(const bf16x8*)(lds_raw + buf*ABYTES + row*128 + ch*16);
  };
  auto rdB = [&](int buf, int n, int kh)->bf16x8 {
    int row = wn*(BN/WN) + n*16 + r;
    int ch = (kh*4 + kq) ^ swz(row);
    return *(const bf16x8*)(lds_raw + 2*ABYTES + buf*BBYTES + row*128 + ch*16);
  };

  const int nt = K/64;
  stage(0, 0);
  for (int t=0; t<nt; ++t){
    asm volatile("s_waitcnt vmcnt(0)" ::: "memory");
    __builtin_amdgcn_s_barrier();
    if (t+1 < nt) stage((t+1)&1, (t+1)*64);
    const int buf = t & 1;
    #pragma unroll
    for (int kh=0; kh<2; ++kh){
      bf16x8 av[MF], bv[NF];
      #pragma unroll
      for (int m=0;m<MF;m++) av[m] = rdA(buf, m, kh);
      #pragma unroll
      for (int n=0;n<NF;n++) bv[n] = rdB(buf, n, kh);
      #pragma unroll
      for (int m=0;m<MF;m++)
        #pragma unroll
        for (int n=0;n<NF;n++)
          acc[m][n] = __builtin_amdgcn_mfma_f32_16x16x32_bf16(av[m], bv[n], acc[m][n], 0, 0, 0);
    }
  }

  #pragma unroll
  for (int m=0;m<MF;m++)
    #pragma unroll
    for (int n=0;n<NF;n++)
      #pragma unroll
      for (int j=0;j<4;j++){
        int gr = tm*BM + wm*(BM/WM) + m*16 + kq*4 + j;
        int gc = tn*BN + wn*(BN/WN) + n*16 + r;
        if (OUTF32) ((float*)C)[(size_t)gr*N + gc] = acc[m][n][j];
        else ((unsigned short*)C)[(size_t)gr*N + gc] = f2bf(acc[m][n][j]);
      }
}

// ---------------- attention v3b (unchanged from r7, passing) ----------------
__global__ __launch_bounds__(256, 2) void attn_fwd3(const unsigned short* __restrict__ QKV,
                                                    const unsigned short* __restrict__ Vt,
                                                    unsigned short* __restrict__ AO){
  __shared__ unsigned short Ks[2][64*128];
  __shared__ unsigned short Vs[2][128*64];
  __shared__ float Ls[4][32];
  const int tid = threadIdx.x;
  const int lane = tid & 63, wv = tid >> 6;
  const int bid = blockIdx.x;
  const int h = bid & 31;
  const int qt = (S_LEN/128 - 1) - (bid >> 5);
  const int kvh = h >> 2;
  const int qb = qt * 128;
  const int q0w = qb + wv * 32;
  const int l31 = lane & 31, g = lane >> 5;
  const int qg = q0w + l31;

  const float CS = 0.12751743f;
  const float C0 = 17.312340f;

  bf16x8 qf[8];
  #pragma unroll
  for (int st=0; st<8; ++st)
    qf[st] = *(const bf16x8*)&QKV[(size_t)qg*QKVN + h*HDIM + st*16 + g*8];

  f32x16 oacc[4];
  #pragma unroll
  for (int db=0; db<4; ++db)
    #pragma unroll
    for (int i=0;i<16;i++) oacc[db][i] = 0.f;
  float lsum = 0.f;

  const unsigned short* Kbase = QKV + KOFS + kvh*HDIM;
  const unsigned short* Vbase = Vt + (size_t)kvh*HDIM*S_LEN;

  auto stage = [&](int buf, int kv0){
    #pragma unroll
    for (int l=0; l<4; ++l){
      int c = l*256 + tid;
      int row = c >> 4, ch = c & 15;
      __builtin_amdgcn_global_load_lds(
        (const AS1 void*)(Kbase + (size_t)(kv0+row)*QKVN + ((ch ^ (row&15))*8)),
        (AS3 void*)((char*)&Ks[buf][0] + (l*256 + wv*64)*16), 16, 0, 0);
    }
    #pragma unroll
    for (int l=0; l<4; ++l){
      int c = l*256 + tid;
      int row = c >> 3, ch = c & 7;
      __builtin_amdgcn_global_load_lds(
        (const AS1 void*)(Vbase + (size_t)row*S_LEN + kv0 + ((ch ^ (row&7))*8)),
        (AS3 void*)((char*)&Vs[buf][0] + (l*256 + wv*64)*16), 16, 0, 0);
    }
  };

  const int nt = 2*qt + 2;
  stage(0, 0);
  for (int t=0; t<nt; ++t){
    __syncthreads();
    if (t+1 < nt) stage((t+1)&1, (t+1)*64);
    const int kv0 = t*64;
    if (kv0 > q0w + 31) continue;
    const unsigned short* K_ = &Ks[t&1][0];
    const unsigned short* V_ = &Vs[t&1][0];

    f32x16 a0, a1;
    #pragma unroll
    for (int i=0;i<16;i++){ a0[i]=0.f; a1[i]=0.f; }
    #pragma unroll
    for (int st=0; st<8; ++st){
      int ch = (2*st + g) ^ (l31 & 15);
      bf16x8 k0 = *(const bf16x8*)&K_[ l31*128      + ch*8 ];
      int ch1 = (2*st + g) ^ ((32+l31) & 15);
      bf16x8 k1 = *(const bf16x8*)&K_[ (32+l31)*128 + ch1*8 ];
      a0 = __builtin_amdgcn_mfma_f32_32x32x16_bf16(k0, qf[st], a0, 0,0,0);
      a1 = __builtin_amdgcn_mfma_f32_32x32x16_bf16(k1, qf[st], a1, 0,0,0);
    }

    float p0[16], p1[16];
    const bool dm = (kv0 + 63 > q0w);
    const int lim = qg - kv0 - 4*g;
    #pragma unroll
    for (int i=0;i<16;i++){
      const int co = (i&3) + 8*(i>>2);
      float e0 = fmaf(a0[i], CS, -C0);
      float e1 = fmaf(a1[i], CS, -C0);
      if (dm){
        if (co      > lim) e0 = -200.f;
        if (co + 32 > lim) e1 = -200.f;
      }
      p0[i] = exp2f(fminf(e0, 60.f));
      p1[i] = exp2f(fminf(e1, 60.f));
    }
    {
      float u0 = (p0[0]+p0[1])+(p0[2]+p0[3]);
      float u1 = (p0[4]+p0[5])+(p0[6]+p0[7]);
      float u2 = (p0[8]+p0[9])+(p0[10]+p0[11]);
      float u3 = (p0[12]+p0[13])+(p0[14]+p0[15]);
      float v0 = (p1[0]+p1[1])+(p1[2]+p1[3]);
      float v1 = (p1[4]+p1[5])+(p1[6]+p1[7]);
      float v2 = (p1[8]+p1[9])+(p1[10]+p1[11]);
      float v3 = (p1[12]+p1[13])+(p1[14]+p1[15]);
      lsum += ((u0+u1)+(u2+u3)) + ((v0+v1)+(v2+v3));
    }

    bf16x8 pa[4];
    #pragma unroll
    for (int u=0; u<4; ++u){
      const float* P = (u<2) ? p0 : p1;
      const int i0 = 8*(u&1);
      unsigned int w0,w1,w2,w3;
      asm("v_cvt_pk_bf16_f32 %0, %1, %2" : "=v"(w0) : "v"(P[i0+0]), "v"(P[i0+1]));
      asm("v_cvt_pk_bf16_f32 %0, %1, %2" : "=v"(w1) : "v"(P[i0+2]), "v"(P[i0+3]));
      asm("v_cvt_pk_bf16_f32 %0, %1, %2" : "=v"(w2) : "v"(P[i0+4]), "v"(P[i0+5]));
      asm("v_cvt_pk_bf16_f32 %0, %1, %2" : "=v"(w3) : "v"(P[i0+6]), "v"(P[i0+7]));
      unsigned int r0 = __shfl_xor(g ? w0 : w2, 32);
      unsigned int r1 = __shfl_xor(g ? w1 : w3, 32);
      union { unsigned int u4[4]; bf16x8 v; } pk;
      pk.u4[0] = g ? r0 : w0;
      pk.u4[1] = g ? r1 : w1;
      pk.u4[2] = g ? w2 : r0;
      pk.u4[3] = g ? w3 : r1;
      pa[u] = pk.v;
    }

    #pragma unroll
    for (int u=0; u<4; ++u)
      #pragma unroll
      for (int db=0; db<4; ++db){
        int row = db*32 + l31;
        int ch = (2*u + g) ^ (row & 7);
        bf16x8 vb = *(const bf16x8*)&V_[row*64 + ch*8];
        oacc[db] = __builtin_amdgcn_mfma_f32_32x32x16_bf16(pa[u], vb, oacc[db], 0,0,0);
      }
  }

  float ls = lsum + __shfl_xor(lsum, 32);
  float inv = 1.0f / fmaxf(ls, 1e-30f);
  Ls[wv][l31] = inv;
  #pragma unroll
  for (int ib=0; ib<4; ++ib){
    float4 iv = *(const float4*)&Ls[wv][8*ib + 4*g];
    float ivv[4] = {iv.x, iv.y, iv.z, iv.w};
    #pragma unroll
    for (int c3=0; c3<4; ++c3){
      int row = 8*ib + 4*g + c3;
      #pragma unroll
      for (int db=0; db<4; ++db){
        AO[(size_t)(qb + wv*32 + row)*HID + h*HDIM + db*32 + l31] =
          f2bf(oacc[db][4*ib+c3] * ivv[c3]);
      }
    }
  }
}

// ---------------- launch ----------------
extern "C" void kernel_launch(void* const* d_in, const int* in_sizes, int n_in,
                              void* d_out, int out_size, void* d_ws, size_t ws_size,
                              hipStream_t stream){
  (void)in_sizes; (void)n_in; (void)out_size; (void)ws_size;
  const float* hs = (const float*)d_in[0];
  const float* Wq = (const float*)d_in[1];
  const float* Wk = (const float*)d_in[2];
  const float* Wv = (const float*)d_in[3];
  const float* Wo = (const float*)d_in[4];
  float* out = (float*)d_out;
  char* ws = (char*)d_ws;
  size_t off = 0;
  auto alloc = [&](size_t bytes)->void*{ void* p = ws + off; off += (bytes + 255) & ~(size_t)255; return p; };

  unsigned short* Hb    = (unsigned short*)alloc((size_t)S_LEN*HID*2);
  unsigned short* Wqkvb = (unsigned short*)alloc((size_t)QKVN*HID*2);
  unsigned short* Wob   = (unsigned short*)alloc((size_t)HID*HID*2);
  unsigned short* QKVb  = (unsigned short*)alloc((size_t)S_LEN*QKVN*2);
  unsigned short* AOb   = (unsigned short*)alloc((size_t)S_LEN*HID*2);
  unsigned short* Vtb   = (unsigned short*)alloc((size_t)NKVH*HDIM*S_LEN*2);
  float* cosT = (float*)alloc((size_t)S_LEN*64*4);
  float* sinT = (float*)alloc((size_t)S_LEN*64*4);

  cvt_all<<<2048, 256, 0, stream>>>(hs, Wq, Wk, Wv, Wo, Hb, Wqkvb, Wob);
  rope_table<<<(S_LEN*64)/256, 256, 0, stream>>>(cosT, sinT);

  // fused QKV projection: BM=128, BN=192, 4 waves 1Mx4N -> grid 32x16 = 512 blocks (2/CU)
  gemm_fr<128,192,1,4,0><<<dim3(QKVN/192, S_LEN/128), 256, 0, stream>>>(Hb, Wqkvb, QKVb, S_LEN, QKVN, HID);

  transpose_v<<<dim3(S_LEN/64, NKVH), 256, 0, stream>>>(QKVb, Vtb);

  // merged Q+K rope (one launch)
  {
    int total = S_LEN*NHEADS*64 + S_LEN*NKVH*64;
    rope_apply2<<<(total+255)/256, 256, 0, stream>>>(QKVb, cosT, sinT);
  }

  // attention: 16 q-tiles of 128 (descending) x 32 heads = 512 blocks
  attn_fwd3<<<dim3(512), 256, 0, stream>>>(QKVb, Vtb, AOb);

  // output projection: BM=128, BN=128, 4 waves 2Mx2N -> grid 32x16 = 512 blocks (2/CU)
  gemm_fr<128,128,2,2,1><<<dim3(HID/128, S_LEN/128), 256, 0, stream>>>(AOb, Wob, out, S_LEN, HID, HID);
}

// Round 9
// 288.140 us; speedup vs baseline: 2.3340x; 1.0365x over previous
//
#include <hip/hip_runtime.h>

typedef __attribute__((ext_vector_type(8))) short bf16x8;
typedef __attribute__((ext_vector_type(4))) short bf16x4;
typedef __attribute__((ext_vector_type(4))) float f32x4;
typedef __attribute__((ext_vector_type(16))) float f32x16;

#define S_LEN  2048
#define HID    4096
#define NHEADS 32
#define NKVH   8
#define HDIM   128
#define QKVN   (HID + 2*NKVH*HDIM)   // 6144
#define KOFS   HID
#define VOFS   (HID + NKVH*HDIM)

#define AS1 __attribute__((address_space(1)))
#define AS3 __attribute__((address_space(3)))

__device__ __forceinline__ unsigned short f2bf(float f){
  unsigned int x = __float_as_uint(f);
  x += 0x7fffu + ((x >> 16) & 1u);
  return (unsigned short)(x >> 16);
}
__device__ __forceinline__ float bf2f(unsigned short h){
  return __uint_as_float(((unsigned int)h) << 16);
}

// ---------------- fused fp32 -> bf16 conversion (all 5 tensors, one launch) ----
__global__ void cvt_all(const float* __restrict__ hs, const float* __restrict__ wq,
                        const float* __restrict__ wk, const float* __restrict__ wv,
                        const float* __restrict__ wo,
                        unsigned short* __restrict__ Hb,
                        unsigned short* __restrict__ Wqkvb,
                        unsigned short* __restrict__ Wob){
  const int total = 12582912;
  for (int i = blockIdx.x * blockDim.x + threadIdx.x; i < total; i += gridDim.x * blockDim.x){
    const float* src; unsigned short* dst;
    if (i < 2097152)      { src = hs + (size_t)i*4;             dst = Hb    + (size_t)i*4; }
    else if (i < 6291456) { size_t l = i - 2097152;  src = wq + l*4; dst = Wqkvb + l*4; }
    else if (i < 7340032) { size_t l = i - 6291456;  src = wk + l*4; dst = Wqkvb + 16777216 + l*4; }
    else if (i < 8388608) { size_t l = i - 7340032;  src = wv + l*4; dst = Wqkvb + 20971520 + l*4; }
    else                  { size_t l = i - 8388608;  src = wo + l*4; dst = Wob   + l*4; }
    float4 v = *(const float4*)src;
    ushort4 o;
    o.x = f2bf(v.x); o.y = f2bf(v.y); o.z = f2bf(v.z); o.w = f2bf(v.w);
    *(ushort4*)dst = o;
  }
}

// ---------------- RoPE ----------------
__global__ void rope_table(float* __restrict__ cosT, float* __restrict__ sinT){
  int idx = blockIdx.x * blockDim.x + threadIdx.x;
  int s = idx >> 6, i = idx & 63;
  float inv = expf(-(float)i * (13.122363377404329f / 64.0f));
  float a = (float)s * inv;
  cosT[idx] = cosf(a);
  sinT[idx] = sinf(a);
}

// merged Q+K rope (one launch)
__global__ void rope_apply2(unsigned short* __restrict__ X, const float* __restrict__ cosT,
                            const float* __restrict__ sinT){
  const int totQ = S_LEN*NHEADS*64;
  const int total = totQ + S_LEN*NKVH*64;
  int idx = blockIdx.x * blockDim.x + threadIdx.x;
  if (idx >= total) return;
  int nh, colofs, local;
  if (idx < totQ){ nh = NHEADS; colofs = 0;    local = idx; }
  else           { nh = NKVH;   colofs = KOFS; local = idx - totQ; }
  int i = local & 63;
  int h = (local >> 6) % nh;
  int s = local / (64*nh);
  size_t base = (size_t)s*QKVN + colofs + h*HDIM + i;
  float x0 = bf2f(X[base]), x1 = bf2f(X[base+64]);
  float c = cosT[(s<<6)|i], sn = sinT[(s<<6)|i];
  X[base]    = f2bf(x0*c - x1*sn);
  X[base+64] = f2bf(x1*c + x0*sn);
}

// ---------------- V transpose: Vt[kvh][d][s] (unchanged) ----------------
__global__ __launch_bounds__(256) void transpose_v(const unsigned short* __restrict__ QKV,
                                                   unsigned short* __restrict__ Vt){
  __shared__ unsigned short T[64][130];
  const int qt = blockIdx.x, kvh = blockIdx.y;
  const int tid = threadIdx.x;
  #pragma unroll
  for (int i=0;i<4;i++){
    int c = tid + i*256;
    int sl = c >> 4;
    int d0 = (c & 15) * 8;
    bf16x8 v = *(const bf16x8*)&QKV[(size_t)(qt*64+sl)*QKVN + VOFS + kvh*HDIM + d0];
    #pragma unroll
    for (int j=0;j<8;j++) T[sl][d0+j] = (unsigned short)v[j];
  }
  __syncthreads();
  #pragma unroll
  for (int i=0;i<4;i++){
    int c = tid + i*256;
    int d = c >> 3;
    int p0 = (c & 7) * 8;
    bf16x8 o;
    #pragma unroll
    for (int j=0;j<8;j++) o[j] = (short)T[p0+j][d];
    *(bf16x8*)&Vt[((size_t)kvh*HDIM + d)*S_LEN + qt*64 + p0] = o;
  }
}

// ---- free-run bf16 GEMM v5: C[M,N] = A[M,K] @ W[N,K]^T ---------------------
// Explicit per-wave software pipeline: issue ALL fragment ds_reads (both
// kh-halves) before any MFMA. lgkmcnt is in-order, so the compiler waits only
// for the kh0 half before the kh0 MFMA cluster; the kh1 reads drain on the
// LDS pipe UNDER kh0's MFMAs, and stage(t+1) gloads run under kh1 — forces
// LDS/MFMA pipe overlap independent of inter-block phase alignment.
// BK=64, full-spread XOR swizzle (involution on gload source + ds_read).
template<int BM, int BN, int WM, int WN, int OUTF32>
__global__ __launch_bounds__(256, 2) void gemm_fr(const unsigned short* __restrict__ A,
                                                  const unsigned short* __restrict__ W,
                                                  void* __restrict__ C, int M, int N, int K){
  constexpr int MF = (BM/WM)/16;
  constexpr int NF = (BN/WN)/16;
  constexpr int LA = BM/32;
  constexpr int LB = BN/32;
  constexpr int ABYTES = BM*128;
  constexpr int BBYTES = BN*128;
  __shared__ char lds_raw[2*ABYTES + 2*BBYTES];

  const int tid = threadIdx.x;
  const int lane = tid & 63, wv = tid >> 6;
  const int wm = wv / WN, wn = wv % WN;
  const int r = lane & 15, kq = lane >> 4;
  const int tn = blockIdx.x, tm = blockIdx.y;
  const unsigned short* Ab = A + (size_t)tm*BM*K;
  const unsigned short* Wb = W + (size_t)tn*BN*K;

  f32x4 acc[MF][NF];
  #pragma unroll
  for (int m=0;m<MF;m++)
    #pragma unroll
    for (int n=0;n<NF;n++) acc[m][n] = {0.f,0.f,0.f,0.f};

  auto swz = [](int row)->int { return ((row>>1)&3)<<1; };

  auto stage = [&](int buf, int kt){
    #pragma unroll
    for (int l=0;l<LA;l++){
      int c = l*256 + tid;
      int row = c >> 3, ch = c & 7;
      __builtin_amdgcn_global_load_lds(
        (const AS1 void*)(Ab + (size_t)row*K + kt + ((ch ^ swz(row))*8)),
        (AS3 void*)(lds_raw + buf*ABYTES + (l*256 + wv*64)*16), 16, 0, 0);
    }
    #pragma unroll
    for (int l=0;l<LB;l++){
      int c = l*256 + tid;
      int row = c >> 3, ch = c & 7;
      __builtin_amdgcn_global_load_lds(
        (const AS1 void*)(Wb + (size_t)row*K + kt + ((ch ^ swz(row))*8)),
        (AS3 void*)(lds_raw + 2*ABYTES + buf*BBYTES + (l*256 + wv*64)*16), 16, 0, 0);
    }
  };
  auto rdA = [&](int buf, int m, int kh)->bf16x8 {
    int row = wm*(BM/WM) + m*16 + r;
    int ch = (kh*4 + kq) ^ swz(row);
    return *(const bf16x8*)(lds_raw + buf*ABYTES + row*128 + ch*16);
  };
  auto rdB = [&](int buf, int n, int kh)->bf16x8 {
    int row = wn*(BN/WN) + n*16 + r;
    int ch = (kh*4 + kq) ^ swz(row);
    return *(const bf16x8*)(lds_raw + 2*ABYTES + buf*BBYTES + row*128 + ch*16);
  };

  const int nt = K/64;
  stage(0, 0);
  for (int t=0; t<nt; ++t){
    asm volatile("s_waitcnt vmcnt(0)" ::: "memory");
    __builtin_amdgcn_s_barrier();
    const int buf = t & 1;
    // issue ALL fragment reads (both kh-halves) before any MFMA
    bf16x8 av0[MF], bv0[NF], av1[MF], bv1[NF];
    #pragma unroll
    for (int m=0;m<MF;m++) av0[m] = rdA(buf, m, 0);
    #pragma unroll
    for (int n=0;n<NF;n++) bv0[n] = rdB(buf, n, 0);
    #pragma unroll
    for (int m=0;m<MF;m++) av1[m] = rdA(buf, m, 1);
    #pragma unroll
    for (int n=0;n<NF;n++) bv1[n] = rdB(buf, n, 1);
    // next-tile staging issues behind the ds_reads
    if (t+1 < nt) stage((t+1)&1, (t+1)*64);
    // kh0 cluster: needs only the first MF+NF reads (in-order lgkmcnt);
    // kh1 reads + gloads drain underneath
    #pragma unroll
    for (int m=0;m<MF;m++)
      #pragma unroll
      for (int n=0;n<NF;n++)
        acc[m][n] = __builtin_amdgcn_mfma_f32_16x16x32_bf16(av0[m], bv0[n], acc[m][n], 0, 0, 0);
    #pragma unroll
    for (int m=0;m<MF;m++)
      #pragma unroll
      for (int n=0;n<NF;n++)
        acc[m][n] = __builtin_amdgcn_mfma_f32_16x16x32_bf16(av1[m], bv1[n], acc[m][n], 0, 0, 0);
  }

  #pragma unroll
  for (int m=0;m<MF;m++)
    #pragma unroll
    for (int n=0;n<NF;n++)
      #pragma unroll
      for (int j=0;j<4;j++){
        int gr = tm*BM + wm*(BM/WM) + m*16 + kq*4 + j;
        int gc = tn*BN + wn*(BN/WN) + n*16 + r;
        if (OUTF32) ((float*)C)[(size_t)gr*N + gc] = acc[m][n][j];
        else ((unsigned short*)C)[(size_t)gr*N + gc] = f2bf(acc[m][n][j]);
      }
}

// ---------------- attention v3b (unchanged, passing) ----------------
__global__ __launch_bounds__(256, 2) void attn_fwd3(const unsigned short* __restrict__ QKV,
                                                    const unsigned short* __restrict__ Vt,
                                                    unsigned short* __restrict__ AO){
  __shared__ unsigned short Ks[2][64*128];
  __shared__ unsigned short Vs[2][128*64];
  __shared__ float Ls[4][32];
  const int tid = threadIdx.x;
  const int lane = tid & 63, wv = tid >> 6;
  const int bid = blockIdx.x;
  const int h = bid & 31;
  const int qt = (S_LEN/128 - 1) - (bid >> 5);
  const int kvh = h >> 2;
  const int qb = qt * 128;
  const int q0w = qb + wv * 32;
  const int l31 = lane & 31, g = lane >> 5;
  const int qg = q0w + l31;

  const float CS = 0.12751743f;
  const float C0 = 17.312340f;

  bf16x8 qf[8];
  #pragma unroll
  for (int st=0; st<8; ++st)
    qf[st] = *(const bf16x8*)&QKV[(size_t)qg*QKVN + h*HDIM + st*16 + g*8];

  f32x16 oacc[4];
  #pragma unroll
  for (int db=0; db<4; ++db)
    #pragma unroll
    for (int i=0;i<16;i++) oacc[db][i] = 0.f;
  float lsum = 0.f;

  const unsigned short* Kbase = QKV + KOFS + kvh*HDIM;
  const unsigned short* Vbase = Vt + (size_t)kvh*HDIM*S_LEN;

  auto stage = [&](int buf, int kv0){
    #pragma unroll
    for (int l=0; l<4; ++l){
      int c = l*256 + tid;
      int row = c >> 4, ch = c & 15;
      __builtin_amdgcn_global_load_lds(
        (const AS1 void*)(Kbase + (size_t)(kv0+row)*QKVN + ((ch ^ (row&15))*8)),
        (AS3 void*)((char*)&Ks[buf][0] + (l*256 + wv*64)*16), 16, 0, 0);
    }
    #pragma unroll
    for (int l=0; l<4; ++l){
      int c = l*256 + tid;
      int row = c >> 3, ch = c & 7;
      __builtin_amdgcn_global_load_lds(
        (const AS1 void*)(Vbase + (size_t)row*S_LEN + kv0 + ((ch ^ (row&7))*8)),
        (AS3 void*)((char*)&Vs[buf][0] + (l*256 + wv*64)*16), 16, 0, 0);
    }
  };

  const int nt = 2*qt + 2;
  stage(0, 0);
  for (int t=0; t<nt; ++t){
    __syncthreads();
    if (t+1 < nt) stage((t+1)&1, (t+1)*64);
    const int kv0 = t*64;
    if (kv0 > q0w + 31) continue;
    const unsigned short* K_ = &Ks[t&1][0];
    const unsigned short* V_ = &Vs[t&1][0];

    f32x16 a0, a1;
    #pragma unroll
    for (int i=0;i<16;i++){ a0[i]=0.f; a1[i]=0.f; }
    #pragma unroll
    for (int st=0; st<8; ++st){
      int ch = (2*st + g) ^ (l31 & 15);
      bf16x8 k0 = *(const bf16x8*)&K_[ l31*128      + ch*8 ];
      int ch1 = (2*st + g) ^ ((32+l31) & 15);
      bf16x8 k1 = *(const bf16x8*)&K_[ (32+l31)*128 + ch1*8 ];
      a0 = __builtin_amdgcn_mfma_f32_32x32x16_bf16(k0, qf[st], a0, 0,0,0);
      a1 = __builtin_amdgcn_mfma_f32_32x32x16_bf16(k1, qf[st], a1, 0,0,0);
    }

    float p0[16], p1[16];
    const bool dm = (kv0 + 63 > q0w);
    const int lim = qg - kv0 - 4*g;
    #pragma unroll
    for (int i=0;i<16;i++){
      const int co = (i&3) + 8*(i>>2);
      float e0 = fmaf(a0[i], CS, -C0);
      float e1 = fmaf(a1[i], CS, -C0);
      if (dm){
        if (co      > lim) e0 = -200.f;
        if (co + 32 > lim) e1 = -200.f;
      }
      p0[i] = exp2f(fminf(e0, 60.f));
      p1[i] = exp2f(fminf(e1, 60.f));
    }
    {
      float u0 = (p0[0]+p0[1])+(p0[2]+p0[3]);
      float u1 = (p0[4]+p0[5])+(p0[6]+p0[7]);
      float u2 = (p0[8]+p0[9])+(p0[10]+p0[11]);
      float u3 = (p0[12]+p0[13])+(p0[14]+p0[15]);
      float v0 = (p1[0]+p1[1])+(p1[2]+p1[3]);
      float v1 = (p1[4]+p1[5])+(p1[6]+p1[7]);
      float v2 = (p1[8]+p1[9])+(p1[10]+p1[11]);
      float v3 = (p1[12]+p1[13])+(p1[14]+p1[15]);
      lsum += ((u0+u1)+(u2+u3)) + ((v0+v1)+(v2+v3));
    }

    bf16x8 pa[4];
    #pragma unroll
    for (int u=0; u<4; ++u){
      const float* P = (u<2) ? p0 : p1;
      const int i0 = 8*(u&1);
      unsigned int w0,w1,w2,w3;
      asm("v_cvt_pk_bf16_f32 %0, %1, %2" : "=v"(w0) : "v"(P[i0+0]), "v"(P[i0+1]));
      asm("v_cvt_pk_bf16_f32 %0, %1, %2" : "=v"(w1) : "v"(P[i0+2]), "v"(P[i0+3]));
      asm("v_cvt_pk_bf16_f32 %0, %1, %2" : "=v"(w2) : "v"(P[i0+4]), "v"(P[i0+5]));
      asm("v_cvt_pk_bf16_f32 %0, %1, %2" : "=v"(w3) : "v"(P[i0+6]), "v"(P[i0+7]));
      unsigned int r0 = __shfl_xor(g ? w0 : w2, 32);
      unsigned int r1 = __shfl_xor(g ? w1 : w3, 32);
      union { unsigned int u4[4]; bf16x8 v; } pk;
      pk.u4[0] = g ? r0 : w0;
      pk.u4[1] = g ? r1 : w1;
      pk.u4[2] = g ? w2 : r0;
      pk.u4[3] = g ? w3 : r1;
      pa[u] = pk.v;
    }

    #pragma unroll
    for (int u=0; u<4; ++u)
      #pragma unroll
      for (int db=0; db<4; ++db){
        int row = db*32 + l31;
        int ch = (2*u + g) ^ (row & 7);
        bf16x8 vb = *(const bf16x8*)&V_[row*64 + ch*8];
        oacc[db] = __builtin_amdgcn_mfma_f32_32x32x16_bf16(pa[u], vb, oacc[db], 0,0,0);
      }
  }

  float ls = lsum + __shfl_xor(lsum, 32);
  float inv = 1.0f / fmaxf(ls, 1e-30f);
  Ls[wv][l31] = inv;
  #pragma unroll
  for (int ib=0; ib<4; ++ib){
    float4 iv = *(const float4*)&Ls[wv][8*ib + 4*g];
    float ivv[4] = {iv.x, iv.y, iv.z, iv.w};
    #pragma unroll
    for (int c3=0; c3<4; ++c3){
      int row = 8*ib + 4*g + c3;
      #pragma unroll
      for (int db=0; db<4; ++db){
        AO[(size_t)(qb + wv*32 + row)*HID + h*HDIM + db*32 + l31] =
          f2bf(oacc[db][4*ib+c3] * ivv[c3]);
      }
    }
  }
}

// ---------------- launch ----------------
extern "C" void kernel_launch(void* const* d_in, const int* in_sizes, int n_in,
                              void* d_out, int out_size, void* d_ws, size_t ws_size,
                              hipStream_t stream){
  (void)in_sizes; (void)n_in; (void)out_size; (void)ws_size;
  const float* hs = (const float*)d_in[0];
  const float* Wq = (const float*)d_in[1];
  const float* Wk = (const float*)d_in[2];
  const float* Wv = (const float*)d_in[3];
  const float* Wo = (const float*)d_in[4];
  float* out = (float*)d_out;
  char* ws = (char*)d_ws;
  size_t off = 0;
  auto alloc = [&](size_t bytes)->void*{ void* p = ws + off; off += (bytes + 255) & ~(size_t)255; return p; };

  unsigned short* Hb    = (unsigned short*)alloc((size_t)S_LEN*HID*2);
  unsigned short* Wqkvb = (unsigned short*)alloc((size_t)QKVN*HID*2);
  unsigned short* Wob   = (unsigned short*)alloc((size_t)HID*HID*2);
  unsigned short* QKVb  = (unsigned short*)alloc((size_t)S_LEN*QKVN*2);
  unsigned short* AOb   = (unsigned short*)alloc((size_t)S_LEN*HID*2);
  unsigned short* Vtb   = (unsigned short*)alloc((size_t)NKVH*HDIM*S_LEN*2);
  float* cosT = (float*)alloc((size_t)S_LEN*64*4);
  float* sinT = (float*)alloc((size_t)S_LEN*64*4);

  cvt_all<<<2048, 256, 0, stream>>>(hs, Wq, Wk, Wv, Wo, Hb, Wqkvb, Wob);
  rope_table<<<(S_LEN*64)/256, 256, 0, stream>>>(cosT, sinT);

  // fused QKV projection: BM=128, BN=192, 4 waves 1Mx4N -> 512 blocks (2/CU)
  gemm_fr<128,192,1,4,0><<<dim3(QKVN/192, S_LEN/128), 256, 0, stream>>>(Hb, Wqkvb, QKVb, S_LEN, QKVN, HID);

  transpose_v<<<dim3(S_LEN/64, NKVH), 256, 0, stream>>>(QKVb, Vtb);

  {
    int total = S_LEN*NHEADS*64 + S_LEN*NKVH*64;
    rope_apply2<<<(total+255)/256, 256, 0, stream>>>(QKVb, cosT, sinT);
  }

  // attention: 16 q-tiles of 128 (descending) x 32 heads = 512 blocks
  attn_fwd3<<<dim3(512), 256, 0, stream>>>(QKVb, Vtb, AOb);

  // output projection: BM=128, BN=128, 4 waves 2Mx2N -> 512 blocks (2/CU)
  gemm_fr<128,128,2,2,1><<<dim3(HID/128, S_LEN/128), 256, 0, stream>>>(AOb, Wob, out, S_LEN, HID, HID);
}